// Round 1
// baseline (5189.508 us; speedup 1.0000x reference)
//
#include <hip/hip_runtime.h>
#include <hip/hip_bf16.h>
#include <hip/hip_cooperative_groups.h>

namespace cg = cooperative_groups;

#define BB_ 64
#define SS_ 50
#define TT_ 25
#define HH_ 1024
#define VV_ 32000

typedef __bf16 bf16x8 __attribute__((ext_vector_type(8)));
typedef float f32x4 __attribute__((ext_vector_type(4)));

__device__ __forceinline__ unsigned short f2b(float f) {
  unsigned u = __float_as_uint(f);
  u = (u + 0x7FFFu + ((u >> 16) & 1u)) >> 16;  // RNE
  return (unsigned short)u;
}
__device__ __forceinline__ float fast_tanh(float x) {
  float e = __expf(2.f * x);
  return 1.f - 2.f / (e + 1.f);
}
__device__ __forceinline__ float fast_sigmoid(float x) {
  return 1.f / (1.f + __expf(-x));
}
__device__ __forceinline__ void gload16(const void* g, void* l) {
  __builtin_amdgcn_global_load_lds((const __attribute__((address_space(1))) void*)g,
                                   (__attribute__((address_space(3))) void*)l, 16, 0, 0);
}
__device__ __forceinline__ bf16x8 ldb8(const unsigned short* p) {
  return *(const bf16x8*)p;
}

// ---------- converts / gathers ----------
__global__ __launch_bounds__(256) void cvt_bf16(const float* __restrict__ src,
                                                unsigned short* __restrict__ dst, long n) {
  long i = ((long)blockIdx.x * 256 + threadIdx.x) * 4;
  if (i >= n) return;
  float4 v = *(const float4*)(src + i);
  *(ushort4*)(dst + i) = make_ushort4(f2b(v.x), f2b(v.y), f2b(v.z), f2b(v.w));
}

__global__ __launch_bounds__(256) void embed_gather(const int* __restrict__ tgt,
                                                    const float* __restrict__ emb,
                                                    unsigned short* __restrict__ X) {
  long idx = ((long)blockIdx.x * 256 + threadIdx.x) * 4;
  if (idx >= (long)1600 * HH_) return;
  int col = (int)(idx & (HH_ - 1));
  int r = (int)(idx >> 10);          // row = b*25 + t
  int t = r % 25;
  int tok = (t == 0) ? 1 : tgt[r - 1];   // SOS=1; tgt flat [B,T]
  float4 v = *(const float4*)(emb + (long)tok * HH_ + col);
  *(ushort4*)(X + idx) = make_ushort4(f2b(v.x), f2b(v.y), f2b(v.z), f2b(v.w));
}

__global__ __launch_bounds__(256) void init_h(const float* __restrict__ eh,
                                              float* __restrict__ Hf,
                                              unsigned short* __restrict__ Hb) {
  int i = (blockIdx.x * 256 + threadIdx.x) * 4;
  if (i >= BB_ * HH_) return;
  float4 v = *(const float4*)(eh + i);
  *(float4*)(Hf + i) = v;
  *(ushort4*)(Hb + i) = make_ushort4(f2b(v.x), f2b(v.y), f2b(v.z), f2b(v.w));
}

// ---------- big GEMM: out[M x ldo] = A[Mpad x 1024](bf16) @ W[N x ldw]^T + bias ----------
// m97 structure: 128x128 tile, BK=32, global_load_lds(16B), 4 waves each 64x64.
// Bijective XCD swizzle (m204): each XCD gets a contiguous run of logical block ids
// (m fastest) so the 13 m-blocks sharing a W-chunk land on the SAME XCD L2.
__global__ __launch_bounds__(256) void gemm128_bt(
    const unsigned short* __restrict__ A, const unsigned short* __restrict__ W,
    const float* __restrict__ bias, float* __restrict__ out, long ldo,
    int Mtiles, int ldw, int Mvalid) {
  __shared__ __align__(16) unsigned short As[128 * 32];
  __shared__ __align__(16) unsigned short Bs[128 * 32];
  int nwg = gridDim.x;
  int orig = blockIdx.x;
  int xcd = orig & 7, lid = orig >> 3;
  int qq = nwg >> 3, rr = nwg & 7;
  int wgid = (xcd < rr ? xcd * (qq + 1) : rr * (qq + 1) + (xcd - rr) * qq) + lid;
  int m0 = (wgid % Mtiles) * 128;
  int n0 = (wgid / Mtiles) * 128;
  int tid = threadIdx.x;
  int w = tid >> 6, l = tid & 63;
  int srow = tid >> 2, scg = tid & 3;
  int mw = (w & 1) * 64, nw = (w >> 1) * 64;

  const unsigned short* Ag0 = A + (long)(m0 + srow) * 1024 + scg * 8;
  const unsigned short* Ag1 = Ag0 + 64 * 1024;
  const unsigned short* Wg0 = W + (long)(n0 + srow) * ldw + scg * 8;
  const unsigned short* Wg1 = Wg0 + (long)64 * ldw;
  unsigned short* lA0 = As + tid * 8;
  unsigned short* lA1 = As + 2048 + tid * 8;
  unsigned short* lB0 = Bs + tid * 8;
  unsigned short* lB1 = Bs + 2048 + tid * 8;

  f32x4 zero = {0.f, 0.f, 0.f, 0.f};
  f32x4 acc[4][4];
#pragma unroll
  for (int i = 0; i < 4; ++i)
#pragma unroll
    for (int j = 0; j < 4; ++j) acc[i][j] = zero;

  for (int k0 = 0; k0 < 1024; k0 += 32) {
    __syncthreads();
    gload16(Ag0 + k0, lA0);
    gload16(Ag1 + k0, lA1);
    gload16(Wg0 + k0, lB0);
    gload16(Wg1 + k0, lB1);
    __syncthreads();
    bf16x8 af[4], bg[4];
#pragma unroll
    for (int mt = 0; mt < 4; ++mt)
      af[mt] = ldb8(As + (mw + mt * 16 + (l & 15)) * 32 + (l >> 4) * 8);
#pragma unroll
    for (int nt = 0; nt < 4; ++nt)
      bg[nt] = ldb8(Bs + (nw + nt * 16 + (l & 15)) * 32 + (l >> 4) * 8);
#pragma unroll
    for (int mt = 0; mt < 4; ++mt)
#pragma unroll
      for (int nt = 0; nt < 4; ++nt)
        acc[mt][nt] = __builtin_amdgcn_mfma_f32_16x16x32_bf16(af[mt], bg[nt], acc[mt][nt], 0, 0, 0);
  }

  int lr = (l >> 4) * 4, lc = l & 15;
#pragma unroll
  for (int nt = 0; nt < 4; ++nt) {
    int col = n0 + nw + nt * 16 + lc;
    float bv = bias[col];
#pragma unroll
    for (int mt = 0; mt < 4; ++mt) {
#pragma unroll
      for (int r = 0; r < 4; ++r) {
        int m = m0 + mw + mt * 16 + lr + r;
        if (m < Mvalid) out[(long)m * ldo + col] = acc[mt][nt][r] + bv;
      }
    }
  }
}

// ---------- fused 25-step decode loop (cooperative, 256 blocks x 256 threads) ----------
// Phase 1: q = h@Wa^T + ba ; gh = h@Whh^T + bhh   (1024 waves, one 16x16 tile each
//          -- identical mapping/math to the old step_qgh)
// Phase 2: attention (blocks 0..63, batch = bid  -- identical math to old step_attn)
// Phase 3: gx_ctx 3-gate GEMM + GRU fuse (wave 0 of every block, tile = bid
//          -- identical math to old step_gru)
// 3 grid.sync() per step replace 3 kernel launches per step.
__global__ __launch_bounds__(256) void decode_loop(
    const unsigned short* __restrict__ WaB, const unsigned short* __restrict__ WhhB,
    const unsigned short* __restrict__ WihB, const float* __restrict__ ba,
    const float* __restrict__ bhh, const float* __restrict__ Va,
    const float* __restrict__ KEYS, const float* __restrict__ enc,
    const float* __restrict__ GA, float* __restrict__ Qf, float* __restrict__ GHf,
    unsigned short* __restrict__ CTXB, float* __restrict__ Hf,
    unsigned short* __restrict__ Hb, unsigned short* __restrict__ HALLB) {
  cg::grid_group grid = cg::this_grid();
  __shared__ float sc[64];
  __shared__ float wgt[64];

  const int tid = threadIdx.x;
  const int bid = blockIdx.x;
  const int l = tid & 63;
  const int lc = l & 15, lr4 = (l >> 4) * 4, ko = (l >> 4) * 8;

  // ---- phase-1 per-wave constants (step-invariant) ----
  const int gw = bid * 4 + (tid >> 6);   // 0..1023
  const int m0 = (gw & 3) * 16;
  const int n = (gw >> 2) * 16;          // 0..4080 over [q:1024 | gh:3072]
  const unsigned short* ApH = Hb + (long)(m0 + lc) * HH_ + ko;
  const unsigned short* B1f;
  float* out1p;
  long ldo1;
  float bv1;
  if (n < 1024) {
    B1f = WaB + (long)(n + lc) * 1024 + ko;
    out1p = Qf + n; ldo1 = 1024; bv1 = ba[n + lc];
  } else {
    B1f = WhhB + (long)(n - 1024 + lc) * 1024 + ko;
    out1p = GHf + (n - 1024); ldo1 = 3072; bv1 = bhh[n - 1024 + lc];
  }

  // ---- phase-3 per-block constants (wave 0 only) ----
  const int m3 = (bid & 3) * 16;
  const int n3 = (bid >> 2) * 16;        // 0..1008
  const unsigned short* Ap3 = CTXB + (long)(m3 + lc) * 1024 + ko;
  const unsigned short* Bg0 = WihB + (long)(n3 + lc) * 2048 + 1024 + ko;
  const unsigned short* Bg1 = Bg0 + (long)1024 * 2048;
  const unsigned short* Bg2 = Bg0 + (long)2048 * 2048;
  const int ig = n3 + lc;

  const f32x4 zero = {0.f, 0.f, 0.f, 0.f};

  for (int t = 0; t < TT_; ++t) {
    // ---- phase 1: q | gh
    {
      f32x4 acc = zero;
#pragma unroll 4
      for (int k = 0; k < 1024; k += 32)
        acc = __builtin_amdgcn_mfma_f32_16x16x32_bf16(ldb8(ApH + k), ldb8(B1f + k), acc, 0, 0, 0);
#pragma unroll
      for (int r = 0; r < 4; ++r)
        out1p[(long)(m0 + lr4 + r) * ldo1 + lc] = acc[r] + bv1;
    }
    grid.sync();

    // ---- phase 2: attention for batch bid (blocks 0..63)
    if (bid < BB_) {
      const int b = bid, w = tid >> 6;
      const float* q = Qf + (long)b * HH_;
      const float* kbase = KEYS + (long)b * SS_ * HH_;
      for (int s = w; s < SS_; s += 4) {
        const float* kr = kbase + (long)s * HH_;
        float p = 0.f;
#pragma unroll
        for (int j = 0; j < 16; ++j) {
          int hh = l + j * 64;
          p += fast_tanh(q[hh] + kr[hh]) * Va[hh];
        }
#pragma unroll
        for (int off = 32; off; off >>= 1) p += __shfl_down(p, off);
        if (l == 0) sc[s] = p;
      }
      __syncthreads();
      if (tid < 64) {  // softmax over 50 in wave 0 (bv shift cancels)
        float v = (tid < SS_) ? sc[tid] : -1e30f;
        float m = v;
#pragma unroll
        for (int off = 32; off; off >>= 1) m = fmaxf(m, __shfl_down(m, off));
        m = __shfl(m, 0);
        float e = (tid < SS_) ? __expf(v - m) : 0.f;
        float ssum = e;
#pragma unroll
        for (int off = 32; off; off >>= 1) ssum += __shfl_down(ssum, off);
        ssum = __shfl(ssum, 0);
        if (tid < SS_) wgt[tid] = e / ssum;
      }
      __syncthreads();
      for (int c = tid; c < HH_; c += 256) {
        float a0 = 0.f;
        const float* ep = enc + (long)b * SS_ * HH_ + c;
#pragma unroll 10
        for (int s = 0; s < SS_; ++s) a0 += wgt[s] * ep[(long)s * HH_];
        CTXB[(long)b * HH_ + c] = f2b(a0);
      }
    }
    grid.sync();

    // ---- phase 3: gx(ctx) 3 gates + GRU fuse -> h_new (wave 0, tile = bid)
    if (tid < 64) {
      f32x4 ar = zero, az = zero, an_ = zero;
#pragma unroll 4
      for (int k = 0; k < 1024; k += 32) {
        bf16x8 a = ldb8(Ap3 + k);
        ar = __builtin_amdgcn_mfma_f32_16x16x32_bf16(a, ldb8(Bg0 + k), ar, 0, 0, 0);
        az = __builtin_amdgcn_mfma_f32_16x16x32_bf16(a, ldb8(Bg1 + k), az, 0, 0, 0);
        an_ = __builtin_amdgcn_mfma_f32_16x16x32_bf16(a, ldb8(Bg2 + k), an_, 0, 0, 0);
      }
#pragma unroll
      for (int r = 0; r < 4; ++r) {
        int bb = m3 + lr4 + r;
        long rowBT = (long)bb * TT_ + t;
        const float* ga = GA + rowBT * 3072;
        const float* gh = GHf + (long)bb * 3072;
        float rr = fast_sigmoid(ga[ig] + ar[r] + gh[ig]);
        float zz = fast_sigmoid(ga[1024 + ig] + az[r] + gh[1024 + ig]);
        float nn = fast_tanh(ga[2048 + ig] + an_[r] + rr * gh[2048 + ig]);
        float hold = Hf[(long)bb * HH_ + ig];
        float hnew = (1.f - zz) * nn + zz * hold;
        Hf[(long)bb * HH_ + ig] = hnew;
        unsigned short hb = f2b(hnew);
        Hb[(long)bb * HH_ + ig] = hb;
        HALLB[rowBT * HH_ + ig] = hb;
      }
    }
    if (t < TT_ - 1) grid.sync();
  }
}

extern "C" void kernel_launch(void* const* d_in, const int* in_sizes, int n_in,
                              void* d_out, int out_size, void* d_ws, size_t ws_size,
                              hipStream_t stream) {
  (void)in_sizes; (void)n_in; (void)out_size; (void)ws_size;
  const float* enc  = (const float*)d_in[0];
  const float* ehid = (const float*)d_in[1];
  const int*   tgt  = (const int*)d_in[2];
  const float* emb  = (const float*)d_in[3];
  const float* Wa   = (const float*)d_in[4];
  const float* ba   = (const float*)d_in[5];
  const float* Ua   = (const float*)d_in[6];
  const float* bu   = (const float*)d_in[7];
  const float* Va   = (const float*)d_in[8];
  const float* Wih  = (const float*)d_in[10];
  const float* bih  = (const float*)d_in[11];
  const float* Whh  = (const float*)d_in[12];
  const float* bhh  = (const float*)d_in[13];
  const float* Wout = (const float*)d_in[14];
  const float* bout = (const float*)d_in[15];
  float* out = (float*)d_out;

  char* p = (char*)d_ws;
  auto alloc = [&](size_t bytes) { char* r = p; p += (bytes + 255) & ~(size_t)255; return r; };
  unsigned short* WOUTB = (unsigned short*)alloc((size_t)VV_ * HH_ * 2);
  unsigned short* WIHB  = (unsigned short*)alloc((size_t)3072 * 2048 * 2);
  unsigned short* WHHB  = (unsigned short*)alloc((size_t)3072 * 1024 * 2);
  unsigned short* WAB   = (unsigned short*)alloc((size_t)1024 * 1024 * 2);
  unsigned short* UAB   = (unsigned short*)alloc((size_t)1024 * 1024 * 2);
  unsigned short* ENCB  = (unsigned short*)alloc((size_t)BB_ * SS_ * HH_ * 2);
  unsigned short* XEMB  = (unsigned short*)alloc((size_t)1664 * HH_ * 2);  // pad 1600->1664
  unsigned short* HALLB = (unsigned short*)alloc((size_t)1664 * HH_ * 2);
  float* KEYS = (float*)alloc((size_t)BB_ * SS_ * HH_ * 4);
  float* GA   = (float*)alloc((size_t)1600 * 3072 * 4);
  float* GHf  = (float*)alloc((size_t)BB_ * 3072 * 4);
  float* Qf   = (float*)alloc((size_t)BB_ * HH_ * 4);
  float* Hf   = (float*)alloc((size_t)BB_ * HH_ * 4);
  unsigned short* Hb = (unsigned short*)alloc((size_t)BB_ * HH_ * 2);
  unsigned short* CTXB = (unsigned short*)alloc((size_t)BB_ * HH_ * 2);

  auto cvt = [&](const float* s, unsigned short* d, long n) {
    cvt_bf16<<<dim3((unsigned)((n / 4 + 255) / 256)), dim3(256), 0, stream>>>(s, d, n);
  };
  cvt(Wout, WOUTB, (long)VV_ * HH_);
  cvt(Wih, WIHB, (long)3072 * 2048);
  cvt(Whh, WHHB, (long)3072 * 1024);
  cvt(Wa, WAB, (long)1024 * 1024);
  cvt(Ua, UAB, (long)1024 * 1024);
  cvt(enc, ENCB, (long)BB_ * SS_ * HH_);
  embed_gather<<<dim3(1600 * HH_ / 4 / 256), dim3(256), 0, stream>>>(tgt, emb, XEMB);
  init_h<<<dim3(BB_ * HH_ / 4 / 256), dim3(256), 0, stream>>>(ehid, Hf, Hb);

  // keys_proj = enc @ Ua^T + bu : [3200,1024]
  gemm128_bt<<<dim3(25 * 8), dim3(256), 0, stream>>>(ENCB, UAB, bu, KEYS, (long)1024, 25, 1024, 3200);
  // gA = Xemb @ W_ih[:, :H]^T + b_ih : [1600,3072]
  gemm128_bt<<<dim3(13 * 24), dim3(256), 0, stream>>>(XEMB, WIHB, bih, GA, (long)3072, 13, 2048, 1600);

  // fused 25-step decode loop (one cooperative dispatch replaces 75 launches)
  void* cargs[] = {(void*)&WAB, (void*)&WHHB, (void*)&WIHB, (void*)&ba, (void*)&bhh,
                   (void*)&Va,  (void*)&KEYS, (void*)&enc,  (void*)&GA, (void*)&Qf,
                   (void*)&GHf, (void*)&CTXB, (void*)&Hf,   (void*)&Hb, (void*)&HALLB};
  hipLaunchCooperativeKernel((const void*)decode_loop, dim3(256), dim3(256),
                             (void**)cargs, 0, stream);

  // logits = Hall @ Wout^T + bout, rows are (b*25+t) -> out[B,T,V] directly
  gemm128_bt<<<dim3(13 * 250), dim3(256), 0, stream>>>(HALLB, WOUTB, bout, out, (long)VV_, 13, 1024, 1600);
}

// Round 2
// 2209.841 us; speedup vs baseline: 2.3484x; 2.3484x over previous
//
#include <hip/hip_runtime.h>
#include <hip/hip_bf16.h>

#define BB_ 64
#define SS_ 50
#define TT_ 25
#define HH_ 1024
#define VV_ 32000

typedef __bf16 bf16x8 __attribute__((ext_vector_type(8)));
typedef float f32x4 __attribute__((ext_vector_type(4)));
typedef unsigned long long u64;

__device__ __forceinline__ unsigned short f2b(float f) {
  unsigned u = __float_as_uint(f);
  u = (u + 0x7FFFu + ((u >> 16) & 1u)) >> 16;  // RNE
  return (unsigned short)u;
}
__device__ __forceinline__ float fast_tanh(float x) {
  float e = __expf(2.f * x);
  return 1.f - 2.f / (e + 1.f);
}
__device__ __forceinline__ float fast_sigmoid(float x) {
  return 1.f / (1.f + __expf(-x));
}
__device__ __forceinline__ void gload16(const void* g, void* l) {
  __builtin_amdgcn_global_load_lds((const __attribute__((address_space(1))) void*)g,
                                   (__attribute__((address_space(3))) void*)l, 16, 0, 0);
}
__device__ __forceinline__ bf16x8 ldb8(const unsigned short* p) {
  return *(const bf16x8*)p;
}

// ---- agent-scope coherent accesses (sc0 sc1): bypass non-coherent L1/per-XCD-L2.
// RELAXED ordering => no buffer_inv / wbl2 emitted => weights stay L2-resident.
__device__ __forceinline__ float cldf(const float* p) {
  return __hip_atomic_load(p, __ATOMIC_RELAXED, __HIP_MEMORY_SCOPE_AGENT);
}
__device__ __forceinline__ void cstf(float* p, float v) {
  __hip_atomic_store(p, v, __ATOMIC_RELAXED, __HIP_MEMORY_SCOPE_AGENT);
}
__device__ __forceinline__ u64 cld8(const u64* p) {
  return __hip_atomic_load(p, __ATOMIC_RELAXED, __HIP_MEMORY_SCOPE_AGENT);
}
__device__ __forceinline__ void cst4(unsigned* p, unsigned v) {
  __hip_atomic_store(p, v, __ATOMIC_RELAXED, __HIP_MEMORY_SCOPE_AGENT);
}

// monotonic grid barrier: __syncthreads drains each wave's vmcnt (coherent stores
// globally visible at ack) before thread 0 signals; relaxed atomics => no cache ops.
__device__ __forceinline__ void gbar(unsigned* cnt, unsigned target) {
  __syncthreads();
  if (threadIdx.x == 0) {
    __hip_atomic_fetch_add(cnt, 1u, __ATOMIC_RELAXED, __HIP_MEMORY_SCOPE_AGENT);
    while (__hip_atomic_load(cnt, __ATOMIC_RELAXED, __HIP_MEMORY_SCOPE_AGENT) < target)
      __builtin_amdgcn_s_sleep(4);
  }
  __syncthreads();
}

// ---------- converts / gathers ----------
__global__ __launch_bounds__(256) void cvt_bf16(const float* __restrict__ src,
                                                unsigned short* __restrict__ dst, long n) {
  long i = ((long)blockIdx.x * 256 + threadIdx.x) * 4;
  if (i >= n) return;
  float4 v = *(const float4*)(src + i);
  *(ushort4*)(dst + i) = make_ushort4(f2b(v.x), f2b(v.y), f2b(v.z), f2b(v.w));
}

__global__ __launch_bounds__(256) void embed_gather(const int* __restrict__ tgt,
                                                    const float* __restrict__ emb,
                                                    unsigned short* __restrict__ X) {
  long idx = ((long)blockIdx.x * 256 + threadIdx.x) * 4;
  if (idx >= (long)1600 * HH_) return;
  int col = (int)(idx & (HH_ - 1));
  int r = (int)(idx >> 10);          // row = b*25 + t
  int t = r % 25;
  int tok = (t == 0) ? 1 : tgt[r - 1];   // SOS=1; tgt flat [B,T]
  float4 v = *(const float4*)(emb + (long)tok * HH_ + col);
  *(ushort4*)(X + idx) = make_ushort4(f2b(v.x), f2b(v.y), f2b(v.z), f2b(v.w));
}

__global__ __launch_bounds__(256) void init_h(const float* __restrict__ eh,
                                              unsigned short* __restrict__ Hb,
                                              unsigned* __restrict__ cnt) {
  if (blockIdx.x == 0 && threadIdx.x == 0) *cnt = 0;   // reset barrier counter each launch
  int i = (blockIdx.x * 256 + threadIdx.x) * 4;
  if (i >= BB_ * HH_) return;
  float4 v = *(const float4*)(eh + i);
  *(ushort4*)(Hb + i) = make_ushort4(f2b(v.x), f2b(v.y), f2b(v.z), f2b(v.w));
}

// ---------- big GEMM: out[M x ldo] = A[Mpad x 1024](bf16) @ W[N x ldw]^T + bias ----------
// m97 structure: 128x128 tile, BK=32, global_load_lds(16B), 4 waves each 64x64.
// Bijective XCD swizzle (m204): consecutive m-blocks (sharing a W chunk) on one XCD L2.
__global__ __launch_bounds__(256) void gemm128_bt(
    const unsigned short* __restrict__ A, const unsigned short* __restrict__ W,
    const float* __restrict__ bias, float* __restrict__ out, long ldo,
    int Mtiles, int ldw, int Mvalid) {
  __shared__ __align__(16) unsigned short As[128 * 32];
  __shared__ __align__(16) unsigned short Bs[128 * 32];
  int nwg = gridDim.x;
  int orig = blockIdx.x;
  int xcd = orig & 7, lid = orig >> 3;
  int qq = nwg >> 3, rr = nwg & 7;
  int wgid = (xcd < rr ? xcd * (qq + 1) : rr * (qq + 1) + (xcd - rr) * qq) + lid;
  int m0 = (wgid % Mtiles) * 128;
  int n0 = (wgid / Mtiles) * 128;
  int tid = threadIdx.x;
  int w = tid >> 6, l = tid & 63;
  int srow = tid >> 2, scg = tid & 3;
  int mw = (w & 1) * 64, nw = (w >> 1) * 64;

  const unsigned short* Ag0 = A + (long)(m0 + srow) * 1024 + scg * 8;
  const unsigned short* Ag1 = Ag0 + 64 * 1024;
  const unsigned short* Wg0 = W + (long)(n0 + srow) * ldw + scg * 8;
  const unsigned short* Wg1 = Wg0 + (long)64 * ldw;
  unsigned short* lA0 = As + tid * 8;
  unsigned short* lA1 = As + 2048 + tid * 8;
  unsigned short* lB0 = Bs + tid * 8;
  unsigned short* lB1 = Bs + 2048 + tid * 8;

  f32x4 zero = {0.f, 0.f, 0.f, 0.f};
  f32x4 acc[4][4];
#pragma unroll
  for (int i = 0; i < 4; ++i)
#pragma unroll
    for (int j = 0; j < 4; ++j) acc[i][j] = zero;

  for (int k0 = 0; k0 < 1024; k0 += 32) {
    __syncthreads();
    gload16(Ag0 + k0, lA0);
    gload16(Ag1 + k0, lA1);
    gload16(Wg0 + k0, lB0);
    gload16(Wg1 + k0, lB1);
    __syncthreads();
    bf16x8 af[4], bg[4];
#pragma unroll
    for (int mt = 0; mt < 4; ++mt)
      af[mt] = ldb8(As + (mw + mt * 16 + (l & 15)) * 32 + (l >> 4) * 8);
#pragma unroll
    for (int nt = 0; nt < 4; ++nt)
      bg[nt] = ldb8(Bs + (nw + nt * 16 + (l & 15)) * 32 + (l >> 4) * 8);
#pragma unroll
    for (int mt = 0; mt < 4; ++mt)
#pragma unroll
      for (int nt = 0; nt < 4; ++nt)
        acc[mt][nt] = __builtin_amdgcn_mfma_f32_16x16x32_bf16(af[mt], bg[nt], acc[mt][nt], 0, 0, 0);
  }

  int lr = (l >> 4) * 4, lc = l & 15;
#pragma unroll
  for (int nt = 0; nt < 4; ++nt) {
    int col = n0 + nw + nt * 16 + lc;
    float bv = bias[col];
#pragma unroll
    for (int mt = 0; mt < 4; ++mt) {
#pragma unroll
      for (int r = 0; r < 4; ++r) {
        int m = m0 + mw + mt * 16 + lr + r;
        if (m < Mvalid) out[(long)m * ldo + col] = acc[mt][nt][r] + bv;
      }
    }
  }
}

// ---------- fused 25-step decode loop (persistent, 256 blocks x 256 threads) ----------
// Inter-phase data (Qf/GHf/CTXB/Hb) flows through agent-coherent (sc0 sc1) accesses;
// barriers are relaxed-atomic monotonic counters => NO L2 flush => weights stay cached.
// A-operands coherent-staged to LDS once per phase (XOR-swizzled, conflict-free b128).
__global__ __launch_bounds__(256) void decode_loop(
    const unsigned short* __restrict__ WaB, const unsigned short* __restrict__ WhhB,
    const unsigned short* __restrict__ WihB, const float* __restrict__ ba,
    const float* __restrict__ bhh, const float* __restrict__ Va,
    const float* __restrict__ KEYS, const float* __restrict__ enc,
    const float* __restrict__ GA, const float* __restrict__ ehid,
    float* __restrict__ Qf, float* __restrict__ GHf,
    unsigned short* __restrict__ CTXB, unsigned short* __restrict__ Hb,
    unsigned short* __restrict__ HALLB, unsigned* __restrict__ cnt) {
  __shared__ __align__(16) char AsC[16 * 2048];   // 16 rows x 1024 bf16 (swizzled)
  __shared__ float qs[1024];
  __shared__ float sc[64];
  __shared__ float wgt[64];

  const int tid = threadIdx.x, bid = blockIdx.x;
  const int wv = tid >> 6, l = tid & 63;
  const int lc = l & 15, hi = l >> 4, ko = hi * 8, lr4 = hi * 4;

  // ---- phase-1 mapping: block owns m-chunk (bid&3), wave owns one 16-col chunk
  const int m1 = (bid & 3) * 16;
  const int nch = (bid >> 2) * 4 + wv;           // 0..255 over [q:64 | gh:192] chunks
  const int n1 = nch * 16;
  const unsigned short* B1;
  float* o1; long ldo1; float bv1;
  if (n1 < 1024) {
    B1 = WaB + (long)(n1 + lc) * 1024 + ko;
    o1 = Qf + n1; ldo1 = 1024; bv1 = ba[n1 + lc];
  } else {
    B1 = WhhB + (long)(n1 - 1024 + lc) * 1024 + ko;
    o1 = GHf + (n1 - 1024); ldo1 = 3072; bv1 = bhh[n1 - 1024 + lc];
  }

  // ---- phase-3 mapping: wave 0 of every block, tile (m3, n3); m3 == m1
  const int m3 = (bid & 3) * 16, n3 = (bid >> 2) * 16;
  const unsigned short* Bg0 = WihB + (long)(n3 + lc) * 2048 + 1024 + ko;
  const unsigned short* Bg1 = Bg0 + (long)1024 * 2048;
  const unsigned short* Bg2 = Bg0 + (long)2048 * 2048;
  const int ig = n3 + lc;
  float hreg[4];
  if (tid < 64) {
#pragma unroll
    for (int r = 0; r < 4; ++r) hreg[r] = ehid[(long)(m3 + lr4 + r) * HH_ + ig];
  }

  const f32x4 zero = {0.f, 0.f, 0.f, 0.f};
  unsigned nbar = 0;

  for (int t = 0; t < TT_; ++t) {
    // ---- phase 1: q | gh  (stage Hb rows m1..m1+15 coherently -> LDS, then MFMA)
    {
#pragma unroll
      for (int i = 0; i < 16; ++i) {
        u64 v = cld8((const u64*)(Hb + (long)(m1 + i) * HH_) + tid);
        *(u64*)(AsC + ((i * 2048 + tid * 8) ^ ((i & 7) << 4))) = v;
      }
      __syncthreads();
      f32x4 acc = zero;
#pragma unroll 8
      for (int k = 0; k < 1024; k += 32) {
        bf16x8 af = *(const bf16x8*)(AsC + ((lc * 2048 + (k + ko) * 2) ^ ((lc & 7) << 4)));
        acc = __builtin_amdgcn_mfma_f32_16x16x32_bf16(af, ldb8(B1 + k), acc, 0, 0, 0);
      }
#pragma unroll
      for (int r = 0; r < 4; ++r)
        cstf(o1 + (long)(m1 + lr4 + r) * ldo1 + lc, acc[r] + bv1);
    }
    gbar(cnt, ++nbar * 256u);

    // ---- phase 2: attention for batch bid (blocks 0..63)
    if (bid < BB_) {
      const int b = bid;
#pragma unroll
      for (int j = 0; j < 4; ++j)
        qs[tid + j * 256] = cldf(Qf + (long)b * HH_ + tid + j * 256);
      __syncthreads();
      const float* kbase = KEYS + (long)b * SS_ * HH_;
      for (int s = wv; s < SS_; s += 4) {
        const float* kr = kbase + (long)s * HH_;
        float p = 0.f;
#pragma unroll
        for (int j = 0; j < 16; ++j) {
          int hh = l + j * 64;
          p += fast_tanh(qs[hh] + kr[hh]) * Va[hh];
        }
#pragma unroll
        for (int off = 32; off; off >>= 1) p += __shfl_down(p, off);
        if (l == 0) sc[s] = p;
      }
      __syncthreads();
      if (tid < 64) {  // softmax over 50 in wave 0 (bv shift cancels)
        float v = (tid < SS_) ? sc[tid] : -1e30f;
        float m = v;
#pragma unroll
        for (int off = 32; off; off >>= 1) m = fmaxf(m, __shfl_down(m, off));
        m = __shfl(m, 0);
        float e = (tid < SS_) ? __expf(v - m) : 0.f;
        float ssum = e;
#pragma unroll
        for (int off = 32; off; off >>= 1) ssum += __shfl_down(ssum, off);
        ssum = __shfl(ssum, 0);
        if (tid < SS_) wgt[tid] = e / ssum;
      }
      __syncthreads();
      {
        int c0 = tid * 4;
        float a0 = 0.f, a1 = 0.f, a2 = 0.f, a3 = 0.f;
        const float* ep = enc + (long)b * SS_ * HH_ + c0;
#pragma unroll 10
        for (int s = 0; s < SS_; ++s) {
          float4 e4 = *(const float4*)(ep + (long)s * HH_);
          float ws_ = wgt[s];
          a0 += ws_ * e4.x; a1 += ws_ * e4.y; a2 += ws_ * e4.z; a3 += ws_ * e4.w;
        }
        unsigned u0 = (unsigned)f2b(a0) | ((unsigned)f2b(a1) << 16);
        unsigned u1 = (unsigned)f2b(a2) | ((unsigned)f2b(a3) << 16);
        cst4((unsigned*)(CTXB + (long)b * HH_ + c0), u0);
        cst4((unsigned*)(CTXB + (long)b * HH_ + c0 + 2), u1);
      }
    }
    gbar(cnt, ++nbar * 256u);

    // ---- phase 3: gx(ctx) 3 gates + GRU fuse -> h_new (wave 0, tile (m3,n3))
    {
#pragma unroll
      for (int i = 0; i < 16; ++i) {   // stage CTXB rows m3..m3+15 (all 4 waves)
        u64 v = cld8((const u64*)(CTXB + (long)(m3 + i) * HH_) + tid);
        *(u64*)(AsC + ((i * 2048 + tid * 8) ^ ((i & 7) << 4))) = v;
      }
      __syncthreads();
      if (tid < 64) {
        f32x4 ar = zero, az = zero, an_ = zero;
#pragma unroll 8
        for (int k = 0; k < 1024; k += 32) {
          bf16x8 a = *(const bf16x8*)(AsC + ((lc * 2048 + (k + ko) * 2) ^ ((lc & 7) << 4)));
          ar = __builtin_amdgcn_mfma_f32_16x16x32_bf16(a, ldb8(Bg0 + k), ar, 0, 0, 0);
          az = __builtin_amdgcn_mfma_f32_16x16x32_bf16(a, ldb8(Bg1 + k), az, 0, 0, 0);
          an_ = __builtin_amdgcn_mfma_f32_16x16x32_bf16(a, ldb8(Bg2 + k), an_, 0, 0, 0);
        }
#pragma unroll
        for (int r = 0; r < 4; ++r) {
          int bb = m3 + lr4 + r;
          long rowBT = (long)bb * TT_ + t;
          const float* ga = GA + rowBT * 3072;
          const float* gh = GHf + (long)bb * 3072;
          float rr = fast_sigmoid(ga[ig] + ar[r] + cldf(gh + ig));
          float zz = fast_sigmoid(ga[1024 + ig] + az[r] + cldf(gh + 1024 + ig));
          float nn = fast_tanh(ga[2048 + ig] + an_[r] + rr * cldf(gh + 2048 + ig));
          float hnew = (1.f - zz) * nn + zz * hreg[r];
          hreg[r] = hnew;
          unsigned hb = (unsigned)f2b(hnew);
          unsigned ob = (unsigned)__shfl_xor((int)hb, 1);
          if ((lc & 1) == 0)
            cst4((unsigned*)(Hb + (long)bb * HH_ + ig), hb | (ob << 16));
          HALLB[rowBT * HH_ + ig] = (unsigned short)hb;
        }
      }
    }
    if (t < TT_ - 1) gbar(cnt, ++nbar * 256u);
  }
}

extern "C" void kernel_launch(void* const* d_in, const int* in_sizes, int n_in,
                              void* d_out, int out_size, void* d_ws, size_t ws_size,
                              hipStream_t stream) {
  (void)in_sizes; (void)n_in; (void)out_size; (void)ws_size;
  const float* enc  = (const float*)d_in[0];
  const float* ehid = (const float*)d_in[1];
  const int*   tgt  = (const int*)d_in[2];
  const float* emb  = (const float*)d_in[3];
  const float* Wa   = (const float*)d_in[4];
  const float* ba   = (const float*)d_in[5];
  const float* Ua   = (const float*)d_in[6];
  const float* bu   = (const float*)d_in[7];
  const float* Va   = (const float*)d_in[8];
  const float* Wih  = (const float*)d_in[10];
  const float* bih  = (const float*)d_in[11];
  const float* Whh  = (const float*)d_in[12];
  const float* bhh  = (const float*)d_in[13];
  const float* Wout = (const float*)d_in[14];
  const float* bout = (const float*)d_in[15];
  float* out = (float*)d_out;

  char* p = (char*)d_ws;
  auto alloc = [&](size_t bytes) { char* r = p; p += (bytes + 255) & ~(size_t)255; return r; };
  unsigned short* WOUTB = (unsigned short*)alloc((size_t)VV_ * HH_ * 2);
  unsigned short* WIHB  = (unsigned short*)alloc((size_t)3072 * 2048 * 2);
  unsigned short* WHHB  = (unsigned short*)alloc((size_t)3072 * 1024 * 2);
  unsigned short* WAB   = (unsigned short*)alloc((size_t)1024 * 1024 * 2);
  unsigned short* UAB   = (unsigned short*)alloc((size_t)1024 * 1024 * 2);
  unsigned short* ENCB  = (unsigned short*)alloc((size_t)BB_ * SS_ * HH_ * 2);
  unsigned short* XEMB  = (unsigned short*)alloc((size_t)1664 * HH_ * 2);  // pad 1600->1664
  unsigned short* HALLB = (unsigned short*)alloc((size_t)1664 * HH_ * 2);
  float* KEYS = (float*)alloc((size_t)BB_ * SS_ * HH_ * 4);
  float* GA   = (float*)alloc((size_t)1600 * 3072 * 4);
  float* GHf  = (float*)alloc((size_t)BB_ * 3072 * 4);
  float* Qf   = (float*)alloc((size_t)BB_ * HH_ * 4);
  unsigned short* Hb = (unsigned short*)alloc((size_t)BB_ * HH_ * 2);
  unsigned short* CTXB = (unsigned short*)alloc((size_t)BB_ * HH_ * 2);
  unsigned* CNT = (unsigned*)alloc(256);

  auto cvt = [&](const float* s, unsigned short* d, long n) {
    cvt_bf16<<<dim3((unsigned)((n / 4 + 255) / 256)), dim3(256), 0, stream>>>(s, d, n);
  };
  cvt(Wout, WOUTB, (long)VV_ * HH_);
  cvt(Wih, WIHB, (long)3072 * 2048);
  cvt(Whh, WHHB, (long)3072 * 1024);
  cvt(Wa, WAB, (long)1024 * 1024);
  cvt(Ua, UAB, (long)1024 * 1024);
  cvt(enc, ENCB, (long)BB_ * SS_ * HH_);
  embed_gather<<<dim3(1600 * HH_ / 4 / 256), dim3(256), 0, stream>>>(tgt, emb, XEMB);
  init_h<<<dim3(BB_ * HH_ / 4 / 256), dim3(256), 0, stream>>>(ehid, Hb, CNT);

  // keys_proj = enc @ Ua^T + bu : [3200,1024]
  gemm128_bt<<<dim3(25 * 8), dim3(256), 0, stream>>>(ENCB, UAB, bu, KEYS, (long)1024, 25, 1024, 3200);
  // gA = Xemb @ W_ih[:, :H]^T + b_ih : [1600,3072]
  gemm128_bt<<<dim3(13 * 24), dim3(256), 0, stream>>>(XEMB, WIHB, bih, GA, (long)3072, 13, 2048, 1600);

  // fused 25-step decode loop (one persistent dispatch; hand-rolled relaxed barriers)
  void* cargs[] = {(void*)&WAB, (void*)&WHHB, (void*)&WIHB, (void*)&ba, (void*)&bhh,
                   (void*)&Va,  (void*)&KEYS, (void*)&enc,  (void*)&GA, (void*)&ehid,
                   (void*)&Qf,  (void*)&GHf,  (void*)&CTXB, (void*)&Hb, (void*)&HALLB,
                   (void*)&CNT};
  hipLaunchCooperativeKernel((const void*)decode_loop, dim3(256), dim3(256),
                             (void**)cargs, 0, stream);

  // logits = Hall @ Wout^T + bout, rows are (b*25+t) -> out[B,T,V] directly
  gemm128_bt<<<dim3(13 * 250), dim3(256), 0, stream>>>(HALLB, WOUTB, bout, out, (long)VV_, 13, 1024, 1600);
}

// Round 3
// 1865.074 us; speedup vs baseline: 2.7825x; 1.1849x over previous
//
#include <hip/hip_runtime.h>
#include <hip/hip_bf16.h>

#define BB_ 64
#define SS_ 50
#define TT_ 25
#define HH_ 1024
#define VV_ 32000

typedef __bf16 bf16x8 __attribute__((ext_vector_type(8)));
typedef float f32x4 __attribute__((ext_vector_type(4)));
typedef unsigned long long u64;

__device__ __forceinline__ unsigned short f2b(float f) {
  unsigned u = __float_as_uint(f);
  u = (u + 0x7FFFu + ((u >> 16) & 1u)) >> 16;  // RNE
  return (unsigned short)u;
}
__device__ __forceinline__ float fast_tanh(float x) {
  float e = __expf(2.f * x);
  return 1.f - 2.f / (e + 1.f);
}
__device__ __forceinline__ float fast_sigmoid(float x) {
  return 1.f / (1.f + __expf(-x));
}
__device__ __forceinline__ void gload16(const void* g, void* l) {
  __builtin_amdgcn_global_load_lds((const __attribute__((address_space(1))) void*)g,
                                   (__attribute__((address_space(3))) void*)l, 16, 0, 0);
}
__device__ __forceinline__ bf16x8 ldb8(const unsigned short* p) {
  return *(const bf16x8*)p;
}

// ---- agent-scope coherent accesses (sc0 sc1): bypass non-coherent L1/per-XCD-L2.
// RELAXED ordering => no buffer_inv / wbl2 emitted => weights stay L2-resident.
__device__ __forceinline__ float cldf(const float* p) {
  return __hip_atomic_load(p, __ATOMIC_RELAXED, __HIP_MEMORY_SCOPE_AGENT);
}
__device__ __forceinline__ void cstf(float* p, float v) {
  __hip_atomic_store(p, v, __ATOMIC_RELAXED, __HIP_MEMORY_SCOPE_AGENT);
}
__device__ __forceinline__ u64 cld8(const u64* p) {
  return __hip_atomic_load(p, __ATOMIC_RELAXED, __HIP_MEMORY_SCOPE_AGENT);
}
__device__ __forceinline__ void cst4(unsigned* p, unsigned v) {
  __hip_atomic_store(p, v, __ATOMIC_RELAXED, __HIP_MEMORY_SCOPE_AGENT);
}
__device__ __forceinline__ unsigned cadd(unsigned* p) {
  return __hip_atomic_fetch_add(p, 1u, __ATOMIC_RELAXED, __HIP_MEMORY_SCOPE_AGENT);
}
__device__ __forceinline__ unsigned cldu(const unsigned* p) {
  return __hip_atomic_load(p, __ATOMIC_RELAXED, __HIP_MEMORY_SCOPE_AGENT);
}

// CNT layout (dwords): [g*32] g<8 group counters | [256] root | [288] epoch
//                      [320] qbar | [384 + b*32] b<64 per-batch mini counters
#define CNT_ROOT 256
#define CNT_EPOCH 288
#define CNT_QBAR 320
#define CNT_MINI 384

// hierarchical grid barrier #n (1-indexed, monotonic): 8 per-XCD-group counters
// (blocks with same bid&7 share an XCD under round-robin dispatch) -> root -> epoch.
__device__ __forceinline__ void gbarG(unsigned* cnt, unsigned n) {
  __syncthreads();   // drains vmcnt -> this block's stores globally visible
  if (threadIdx.x == 0) {
    unsigned g = blockIdx.x & 7u;
    unsigned old = cadd(cnt + g * 32);
    if (old == n * 32u - 1u) {
      unsigned r = cadd(cnt + CNT_ROOT);
      if (r == n * 8u - 1u) cst4(cnt + CNT_EPOCH, n);
    }
    while (cldu(cnt + CNT_EPOCH) < n) __builtin_amdgcn_s_sleep(2);
  }
  __syncthreads();
}

// ---------- converts / gathers ----------
__global__ __launch_bounds__(256) void cvt_bf16(const float* __restrict__ src,
                                                unsigned short* __restrict__ dst, long n) {
  long i = ((long)blockIdx.x * 256 + threadIdx.x) * 4;
  if (i >= n) return;
  float4 v = *(const float4*)(src + i);
  *(ushort4*)(dst + i) = make_ushort4(f2b(v.x), f2b(v.y), f2b(v.z), f2b(v.w));
}

__global__ __launch_bounds__(256) void embed_gather(const int* __restrict__ tgt,
                                                    const float* __restrict__ emb,
                                                    unsigned short* __restrict__ X) {
  long idx = ((long)blockIdx.x * 256 + threadIdx.x) * 4;
  if (idx >= (long)1600 * HH_) return;
  int col = (int)(idx & (HH_ - 1));
  int r = (int)(idx >> 10);          // row = b*25 + t
  int t = r % 25;
  int tok = (t == 0) ? 1 : tgt[r - 1];   // SOS=1; tgt flat [B,T]
  float4 v = *(const float4*)(emb + (long)tok * HH_ + col);
  *(ushort4*)(X + idx) = make_ushort4(f2b(v.x), f2b(v.y), f2b(v.z), f2b(v.w));
}

__global__ __launch_bounds__(256) void init_h(const float* __restrict__ eh,
                                              unsigned short* __restrict__ Hb,
                                              unsigned* __restrict__ cnt) {
  if (blockIdx.x == 0) {   // reset all barrier counters each launch (graph replays!)
    for (int k = threadIdx.x; k < 4096; k += 256) cnt[k] = 0;
  }
  int i = (blockIdx.x * 256 + threadIdx.x) * 4;
  if (i >= BB_ * HH_) return;
  float4 v = *(const float4*)(eh + i);
  *(ushort4*)(Hb + i) = make_ushort4(f2b(v.x), f2b(v.y), f2b(v.z), f2b(v.w));
}

// ---------- big GEMM: out[M x ldo] = A[Mpad x 1024](bf16) @ W[N x ldw]^T + bias ----------
// m97 structure: 128x128 tile, BK=32, global_load_lds(16B), 4 waves each 64x64.
// Bijective XCD swizzle (m204): consecutive m-blocks (sharing a W chunk) on one XCD L2.
__global__ __launch_bounds__(256) void gemm128_bt(
    const unsigned short* __restrict__ A, const unsigned short* __restrict__ W,
    const float* __restrict__ bias, float* __restrict__ out, long ldo,
    int Mtiles, int ldw, int Mvalid) {
  __shared__ __align__(16) unsigned short As[128 * 32];
  __shared__ __align__(16) unsigned short Bs[128 * 32];
  int nwg = gridDim.x;
  int orig = blockIdx.x;
  int xcd = orig & 7, lid = orig >> 3;
  int qq = nwg >> 3, rr = nwg & 7;
  int wgid = (xcd < rr ? xcd * (qq + 1) : rr * (qq + 1) + (xcd - rr) * qq) + lid;
  int m0 = (wgid % Mtiles) * 128;
  int n0 = (wgid / Mtiles) * 128;
  int tid = threadIdx.x;
  int w = tid >> 6, l = tid & 63;
  int srow = tid >> 2, scg = tid & 3;
  int mw = (w & 1) * 64, nw = (w >> 1) * 64;

  const unsigned short* Ag0 = A + (long)(m0 + srow) * 1024 + scg * 8;
  const unsigned short* Ag1 = Ag0 + 64 * 1024;
  const unsigned short* Wg0 = W + (long)(n0 + srow) * ldw + scg * 8;
  const unsigned short* Wg1 = Wg0 + (long)64 * ldw;
  unsigned short* lA0 = As + tid * 8;
  unsigned short* lA1 = As + 2048 + tid * 8;
  unsigned short* lB0 = Bs + tid * 8;
  unsigned short* lB1 = Bs + 2048 + tid * 8;

  f32x4 zero = {0.f, 0.f, 0.f, 0.f};
  f32x4 acc[4][4];
#pragma unroll
  for (int i = 0; i < 4; ++i)
#pragma unroll
    for (int j = 0; j < 4; ++j) acc[i][j] = zero;

  for (int k0 = 0; k0 < 1024; k0 += 32) {
    __syncthreads();
    gload16(Ag0 + k0, lA0);
    gload16(Ag1 + k0, lA1);
    gload16(Wg0 + k0, lB0);
    gload16(Wg1 + k0, lB1);
    __syncthreads();
    bf16x8 af[4], bg[4];
#pragma unroll
    for (int mt = 0; mt < 4; ++mt)
      af[mt] = ldb8(As + (mw + mt * 16 + (l & 15)) * 32 + (l >> 4) * 8);
#pragma unroll
    for (int nt = 0; nt < 4; ++nt)
      bg[nt] = ldb8(Bs + (nw + nt * 16 + (l & 15)) * 32 + (l >> 4) * 8);
#pragma unroll
    for (int mt = 0; mt < 4; ++mt)
#pragma unroll
      for (int nt = 0; nt < 4; ++nt)
        acc[mt][nt] = __builtin_amdgcn_mfma_f32_16x16x32_bf16(af[mt], bg[nt], acc[mt][nt], 0, 0, 0);
  }

  int lr = (l >> 4) * 4, lc = l & 15;
#pragma unroll
  for (int nt = 0; nt < 4; ++nt) {
    int col = n0 + nw + nt * 16 + lc;
    float bv = bias[col];
#pragma unroll
    for (int mt = 0; mt < 4; ++mt) {
#pragma unroll
      for (int r = 0; r < 4; ++r) {
        int m = m0 + mw + mt * 16 + lr + r;
        if (m < Mvalid) out[(long)m * ldo + col] = acc[mt][nt][r] + bv;
      }
    }
  }
}

// ---------- fused 25-step decode loop (persistent, 256 blocks x 256 threads) ----------
// Schedule per step:
//   P1: blocks 0-63 compute q (chunks 0-63), blocks 64-255 compute gh (chunks 64-255)
//       [identical chunk math to round-2: nch=(bid>>2)*4+wv]
//   qbar: 64-producer broadcast (gh overlaps attention from here on)
//   P2a: scores -- 16 waves per batch (4 blocks x 4 waves, s += 16), coherent SC
//   mini-barrier: per-batch 4-block counter
//   P2b: softmax (wave0, identical math) + ctx over a 256-col quarter per block
//   grid barrier (hierarchical)
//   P3: gx 3-gate GEMM + GRU fuse (wave0, identical to round-2)
//   grid barrier
// Streams (KEYS/enc/GA) use non-temporal loads so weight fragments stay L2-resident.
__global__ __launch_bounds__(256) void decode_loop(
    const unsigned short* __restrict__ WaB, const unsigned short* __restrict__ WhhB,
    const unsigned short* __restrict__ WihB, const float* __restrict__ ba,
    const float* __restrict__ bhh, const float* __restrict__ Va,
    const float* __restrict__ KEYS, const float* __restrict__ enc,
    const float* __restrict__ GA, const float* __restrict__ ehid,
    float* __restrict__ Qf, float* __restrict__ GHf, float* __restrict__ SC,
    unsigned short* __restrict__ CTXB, unsigned short* __restrict__ Hb,
    unsigned short* __restrict__ HALLB, unsigned* __restrict__ cnt) {
  __shared__ __align__(16) char AsC[16 * 2048];   // 16 rows x 1024 bf16 (swizzled)
  __shared__ float qs[1024];
  __shared__ float vas[1024];
  __shared__ float wgt[64];

  const int tid = threadIdx.x, bid = blockIdx.x;
  const int wv = tid >> 6, l = tid & 63;
  const int lc = l & 15, hi = l >> 4, ko = hi * 8, lr4 = hi * 4;

  // ---- phase-1 mapping (identical to round 2): wave owns chunk nch of [q:64|gh:192]
  const int m1 = (bid & 3) * 16;
  const int nch = (bid >> 2) * 4 + wv;           // 0..255
  const int n1 = nch * 16;
  const unsigned short* B1;
  float* o1; long ldo1; float bv1;
  if (n1 < 1024) {
    B1 = WaB + (long)(n1 + lc) * 1024 + ko;
    o1 = Qf + n1; ldo1 = 1024; bv1 = ba[n1 + lc];
  } else {
    B1 = WhhB + (long)(n1 - 1024 + lc) * 1024 + ko;
    o1 = GHf + (n1 - 1024); ldo1 = 3072; bv1 = bhh[n1 - 1024 + lc];
  }

  // ---- phase-2 mapping
  const int b2 = bid >> 2;                        // batch
  const int jq = (bid & 3) * 4 + wv;              // 0..15 score-wave id within batch
  const int c2 = (bid & 3) * 256 + tid;           // ctx column

  // ---- phase-3 mapping (identical to round 2)
  const int m3 = (bid & 3) * 16, n3 = (bid >> 2) * 16;
  const unsigned short* Bg0 = WihB + (long)(n3 + lc) * 2048 + 1024 + ko;
  const unsigned short* Bg1 = Bg0 + (long)1024 * 2048;
  const unsigned short* Bg2 = Bg0 + (long)2048 * 2048;
  const int ig = n3 + lc;
  float hreg[4];
  if (tid < 64) {
#pragma unroll
    for (int r = 0; r < 4; ++r) hreg[r] = ehid[(long)(m3 + lr4 + r) * HH_ + ig];
  }

  // stage Va once (static)
#pragma unroll
  for (int j = 0; j < 4; ++j) vas[tid + j * 256] = Va[tid + j * 256];

  const f32x4 zero = {0.f, 0.f, 0.f, 0.f};
  unsigned gB = 0;

  for (int t = 0; t < TT_; ++t) {
    // ---- P1: q (blocks 0-63) | gh (blocks 64-255)
    {
#pragma unroll
      for (int i = 0; i < 16; ++i) {
        u64 v = cld8((const u64*)(Hb + (long)(m1 + i) * HH_) + tid);
        *(u64*)(AsC + ((i * 2048 + tid * 8) ^ ((i & 7) << 4))) = v;
      }
      __syncthreads();
      f32x4 acc = zero;
#pragma unroll 8
      for (int k = 0; k < 1024; k += 32) {
        bf16x8 af = *(const bf16x8*)(AsC + ((lc * 2048 + (k + ko) * 2) ^ ((lc & 7) << 4)));
        acc = __builtin_amdgcn_mfma_f32_16x16x32_bf16(af, ldb8(B1 + k), acc, 0, 0, 0);
      }
#pragma unroll
      for (int r = 0; r < 4; ++r)
        cstf(o1 + (long)(m1 + lr4 + r) * ldo1 + lc, acc[r] + bv1);
    }
    // ---- qbar: q producers (blocks 0-63) signal; everyone waits. gh overlaps attn.
    __syncthreads();
    if (tid == 0) {
      if (bid < 64) cadd(cnt + CNT_QBAR);
      while (cldu(cnt + CNT_QBAR) < (unsigned)(t + 1) * 64u) __builtin_amdgcn_s_sleep(2);
    }
    __syncthreads();

    // ---- P2a: scores for batch b2, this wave handles s = jq, jq+16, ...
    {
#pragma unroll
      for (int j = 0; j < 4; ++j)
        qs[tid + j * 256] = cldf(Qf + (long)b2 * HH_ + tid + j * 256);
      __syncthreads();
      for (int s = jq; s < SS_; s += 16) {
        const float* kr = KEYS + ((long)b2 * SS_ + s) * HH_;
        float p = 0.f;
#pragma unroll
        for (int j = 0; j < 16; ++j) {
          int hh = l + j * 64;
          p += fast_tanh(qs[hh] + __builtin_nontemporal_load(kr + hh)) * vas[hh];
        }
#pragma unroll
        for (int off = 32; off; off >>= 1) p += __shfl_down(p, off);
        if (l == 0) cstf(SC + (long)b2 * 64 + s, p);
      }
    }
    // ---- mini-barrier: the 4 blocks of batch b2
    __syncthreads();
    if (tid == 0) {
      unsigned* mc = cnt + CNT_MINI + b2 * 32;
      cadd(mc);
      while (cldu(mc) < (unsigned)(t + 1) * 4u) __builtin_amdgcn_s_sleep(2);
    }
    __syncthreads();

    // ---- P2b: softmax (identical math) + ctx quarter
    {
      if (tid < 64) {
        float v = (tid < SS_) ? cldf(SC + (long)b2 * 64 + tid) : -1e30f;
        float m = v;
#pragma unroll
        for (int off = 32; off; off >>= 1) m = fmaxf(m, __shfl_down(m, off));
        m = __shfl(m, 0);
        float e = (tid < SS_) ? __expf(v - m) : 0.f;
        float ssum = e;
#pragma unroll
        for (int off = 32; off; off >>= 1) ssum += __shfl_down(ssum, off);
        ssum = __shfl(ssum, 0);
        if (tid < SS_) wgt[tid] = e / ssum;
      }
      __syncthreads();
      {
        const float* ep = enc + (long)b2 * SS_ * HH_ + c2;
        float a0 = 0.f;
#pragma unroll 10
        for (int s = 0; s < SS_; ++s)
          a0 += wgt[s] * __builtin_nontemporal_load(ep + (long)s * HH_);
        unsigned hb16 = (unsigned)f2b(a0);
        unsigned ob = (unsigned)__shfl_xor((int)hb16, 1);
        if ((tid & 1) == 0)
          cst4((unsigned*)(CTXB + (long)b2 * HH_ + c2), hb16 | (ob << 16));
      }
    }
    gbarG(cnt, ++gB);

    // ---- P3: gx(ctx) 3 gates + GRU fuse -> h_new (wave 0, tile (m3,n3))
    {
#pragma unroll
      for (int i = 0; i < 16; ++i) {   // stage CTXB rows m3..m3+15 (all 4 waves)
        u64 v = cld8((const u64*)(CTXB + (long)(m3 + i) * HH_) + tid);
        *(u64*)(AsC + ((i * 2048 + tid * 8) ^ ((i & 7) << 4))) = v;
      }
      __syncthreads();
      if (tid < 64) {
        f32x4 ar = zero, az = zero, an_ = zero;
#pragma unroll 8
        for (int k = 0; k < 1024; k += 32) {
          bf16x8 a = *(const bf16x8*)(AsC + ((lc * 2048 + (k + ko) * 2) ^ ((lc & 7) << 4)));
          ar = __builtin_amdgcn_mfma_f32_16x16x32_bf16(a, ldb8(Bg0 + k), ar, 0, 0, 0);
          az = __builtin_amdgcn_mfma_f32_16x16x32_bf16(a, ldb8(Bg1 + k), az, 0, 0, 0);
          an_ = __builtin_amdgcn_mfma_f32_16x16x32_bf16(a, ldb8(Bg2 + k), an_, 0, 0, 0);
        }
#pragma unroll
        for (int r = 0; r < 4; ++r) {
          int bb = m3 + lr4 + r;
          long rowBT = (long)bb * TT_ + t;
          const float* ga = GA + rowBT * 3072;
          const float* gh = GHf + (long)bb * 3072;
          float rr = fast_sigmoid(__builtin_nontemporal_load(ga + ig) + ar[r] + cldf(gh + ig));
          float zz = fast_sigmoid(__builtin_nontemporal_load(ga + 1024 + ig) + az[r] + cldf(gh + 1024 + ig));
          float nn = fast_tanh(__builtin_nontemporal_load(ga + 2048 + ig) + an_[r] + rr * cldf(gh + 2048 + ig));
          float hnew = (1.f - zz) * nn + zz * hreg[r];
          hreg[r] = hnew;
          unsigned hb = (unsigned)f2b(hnew);
          unsigned ob = (unsigned)__shfl_xor((int)hb, 1);
          if ((lc & 1) == 0)
            cst4((unsigned*)(Hb + (long)bb * HH_ + ig), hb | (ob << 16));
          HALLB[rowBT * HH_ + ig] = (unsigned short)hb;
        }
      }
    }
    if (t < TT_ - 1) gbarG(cnt, ++gB);
  }
}

extern "C" void kernel_launch(void* const* d_in, const int* in_sizes, int n_in,
                              void* d_out, int out_size, void* d_ws, size_t ws_size,
                              hipStream_t stream) {
  (void)in_sizes; (void)n_in; (void)out_size; (void)ws_size;
  const float* enc  = (const float*)d_in[0];
  const float* ehid = (const float*)d_in[1];
  const int*   tgt  = (const int*)d_in[2];
  const float* emb  = (const float*)d_in[3];
  const float* Wa   = (const float*)d_in[4];
  const float* ba   = (const float*)d_in[5];
  const float* Ua   = (const float*)d_in[6];
  const float* bu   = (const float*)d_in[7];
  const float* Va   = (const float*)d_in[8];
  const float* Wih  = (const float*)d_in[10];
  const float* bih  = (const float*)d_in[11];
  const float* Whh  = (const float*)d_in[12];
  const float* bhh  = (const float*)d_in[13];
  const float* Wout = (const float*)d_in[14];
  const float* bout = (const float*)d_in[15];
  float* out = (float*)d_out;

  char* p = (char*)d_ws;
  auto alloc = [&](size_t bytes) { char* r = p; p += (bytes + 255) & ~(size_t)255; return r; };
  unsigned short* WOUTB = (unsigned short*)alloc((size_t)VV_ * HH_ * 2);
  unsigned short* WIHB  = (unsigned short*)alloc((size_t)3072 * 2048 * 2);
  unsigned short* WHHB  = (unsigned short*)alloc((size_t)3072 * 1024 * 2);
  unsigned short* WAB   = (unsigned short*)alloc((size_t)1024 * 1024 * 2);
  unsigned short* UAB   = (unsigned short*)alloc((size_t)1024 * 1024 * 2);
  unsigned short* ENCB  = (unsigned short*)alloc((size_t)BB_ * SS_ * HH_ * 2);
  unsigned short* XEMB  = (unsigned short*)alloc((size_t)1664 * HH_ * 2);  // pad 1600->1664
  unsigned short* HALLB = (unsigned short*)alloc((size_t)1664 * HH_ * 2);
  float* KEYS = (float*)alloc((size_t)BB_ * SS_ * HH_ * 4);
  float* GA   = (float*)alloc((size_t)1600 * 3072 * 4);
  float* GHf  = (float*)alloc((size_t)BB_ * 3072 * 4);
  float* Qf   = (float*)alloc((size_t)BB_ * HH_ * 4);
  float* SCf  = (float*)alloc((size_t)BB_ * 64 * 4);
  unsigned short* Hb = (unsigned short*)alloc((size_t)BB_ * HH_ * 2);
  unsigned short* CTXB = (unsigned short*)alloc((size_t)BB_ * HH_ * 2);
  unsigned* CNT = (unsigned*)alloc(4096 * 4);

  auto cvt = [&](const float* s, unsigned short* d, long n) {
    cvt_bf16<<<dim3((unsigned)((n / 4 + 255) / 256)), dim3(256), 0, stream>>>(s, d, n);
  };
  cvt(Wout, WOUTB, (long)VV_ * HH_);
  cvt(Wih, WIHB, (long)3072 * 2048);
  cvt(Whh, WHHB, (long)3072 * 1024);
  cvt(Wa, WAB, (long)1024 * 1024);
  cvt(Ua, UAB, (long)1024 * 1024);
  cvt(enc, ENCB, (long)BB_ * SS_ * HH_);
  embed_gather<<<dim3(1600 * HH_ / 4 / 256), dim3(256), 0, stream>>>(tgt, emb, XEMB);
  init_h<<<dim3(BB_ * HH_ / 4 / 256), dim3(256), 0, stream>>>(ehid, Hb, CNT);

  // keys_proj = enc @ Ua^T + bu : [3200,1024]
  gemm128_bt<<<dim3(25 * 8), dim3(256), 0, stream>>>(ENCB, UAB, bu, KEYS, (long)1024, 25, 1024, 3200);
  // gA = Xemb @ W_ih[:, :H]^T + b_ih : [1600,3072]
  gemm128_bt<<<dim3(13 * 24), dim3(256), 0, stream>>>(XEMB, WIHB, bih, GA, (long)3072, 13, 2048, 1600);

  // fused 25-step decode loop (one persistent dispatch; hand-rolled relaxed barriers)
  void* cargs[] = {(void*)&WAB, (void*)&WHHB, (void*)&WIHB, (void*)&ba, (void*)&bhh,
                   (void*)&Va,  (void*)&KEYS, (void*)&enc,  (void*)&GA, (void*)&ehid,
                   (void*)&Qf,  (void*)&GHf,  (void*)&SCf,  (void*)&CTXB, (void*)&Hb,
                   (void*)&HALLB, (void*)&CNT};
  hipLaunchCooperativeKernel((const void*)decode_loop, dim3(256), dim3(256),
                             (void**)cargs, 0, stream);

  // logits = Hall @ Wout^T + bout, rows are (b*25+t) -> out[B,T,V] directly
  gemm128_bt<<<dim3(13 * 250), dim3(256), 0, stream>>>(HALLB, WOUTB, bout, out, (long)VV_, 13, 1024, 1600);
}

// Round 4
// 1740.294 us; speedup vs baseline: 2.9820x; 1.0717x over previous
//
#include <hip/hip_runtime.h>
#include <hip/hip_bf16.h>

#define BB_ 64
#define SS_ 50
#define TT_ 25
#define HH_ 1024
#define VV_ 32000

typedef __bf16 bf16x8 __attribute__((ext_vector_type(8)));
typedef float f32x4 __attribute__((ext_vector_type(4)));
typedef unsigned long long u64;

__device__ __forceinline__ unsigned short f2b(float f) {
  unsigned u = __float_as_uint(f);
  u = (u + 0x7FFFu + ((u >> 16) & 1u)) >> 16;  // RNE
  return (unsigned short)u;
}
__device__ __forceinline__ float fast_tanh(float x) {
  float e = __expf(2.f * x);
  return 1.f - 2.f / (e + 1.f);
}
__device__ __forceinline__ float fast_sigmoid(float x) {
  return 1.f / (1.f + __expf(-x));
}
__device__ __forceinline__ void gload16(const void* g, void* l) {
  __builtin_amdgcn_global_load_lds((const __attribute__((address_space(1))) void*)g,
                                   (__attribute__((address_space(3))) void*)l, 16, 0, 0);
}
__device__ __forceinline__ bf16x8 ldb8(const unsigned short* p) {
  return *(const bf16x8*)p;
}

// ---- agent-scope coherent accesses (sc0 sc1): bypass non-coherent L1/per-XCD-L2.
// RELAXED ordering => no buffer_inv / wbl2 emitted => weights stay L2-resident.
// Also used for STREAMING reads (KEYS/enc/GA): no L2 allocation => no weight eviction.
__device__ __forceinline__ float cldf(const float* p) {
  return __hip_atomic_load(p, __ATOMIC_RELAXED, __HIP_MEMORY_SCOPE_AGENT);
}
__device__ __forceinline__ void cstf(float* p, float v) {
  __hip_atomic_store(p, v, __ATOMIC_RELAXED, __HIP_MEMORY_SCOPE_AGENT);
}
__device__ __forceinline__ u64 cld8(const u64* p) {
  return __hip_atomic_load(p, __ATOMIC_RELAXED, __HIP_MEMORY_SCOPE_AGENT);
}
__device__ __forceinline__ void cst4(unsigned* p, unsigned v) {
  __hip_atomic_store(p, v, __ATOMIC_RELAXED, __HIP_MEMORY_SCOPE_AGENT);
}
__device__ __forceinline__ unsigned cadd(unsigned* p) {
  return __hip_atomic_fetch_add(p, 1u, __ATOMIC_RELAXED, __HIP_MEMORY_SCOPE_AGENT);
}
__device__ __forceinline__ unsigned cldu(const unsigned* p) {
  return __hip_atomic_load(p, __ATOMIC_RELAXED, __HIP_MEMORY_SCOPE_AGENT);
}

// CNT layout (dwords): [g*32] g<8 group counters | [256] root | [288] epoch
//                      [320] qbar | [384 + b*32] b<64 per-batch mini counters
#define CNT_ROOT 256
#define CNT_EPOCH 288
#define CNT_QBAR 320
#define CNT_MINI 384

// hierarchical grid barrier #n (1-indexed, monotonic): 8 per-XCD-group counters
// (blocks with same bid&7 share an XCD under round-robin dispatch) -> root -> epoch.
__device__ __forceinline__ void gbarG(unsigned* cnt, unsigned n) {
  __syncthreads();   // drains vmcnt -> this block's stores globally visible
  if (threadIdx.x == 0) {
    unsigned g = blockIdx.x & 7u;
    unsigned old = cadd(cnt + g * 32);
    if (old == n * 32u - 1u) {
      unsigned r = cadd(cnt + CNT_ROOT);
      if (r == n * 8u - 1u) cst4(cnt + CNT_EPOCH, n);
    }
    while (cldu(cnt + CNT_EPOCH) < n) __builtin_amdgcn_s_sleep(2);
  }
  __syncthreads();
}

// ---------- converts / gathers ----------
__global__ __launch_bounds__(256) void cvt_bf16(const float* __restrict__ src,
                                                unsigned short* __restrict__ dst, long n) {
  long i = ((long)blockIdx.x * 256 + threadIdx.x) * 4;
  if (i >= n) return;
  float4 v = *(const float4*)(src + i);
  *(ushort4*)(dst + i) = make_ushort4(f2b(v.x), f2b(v.y), f2b(v.z), f2b(v.w));
}

__global__ __launch_bounds__(256) void embed_gather(const int* __restrict__ tgt,
                                                    const float* __restrict__ emb,
                                                    unsigned short* __restrict__ X) {
  long idx = ((long)blockIdx.x * 256 + threadIdx.x) * 4;
  if (idx >= (long)1600 * HH_) return;
  int col = (int)(idx & (HH_ - 1));
  int r = (int)(idx >> 10);          // row = b*25 + t
  int t = r % 25;
  int tok = (t == 0) ? 1 : tgt[r - 1];   // SOS=1; tgt flat [B,T]
  float4 v = *(const float4*)(emb + (long)tok * HH_ + col);
  *(ushort4*)(X + idx) = make_ushort4(f2b(v.x), f2b(v.y), f2b(v.z), f2b(v.w));
}

__global__ __launch_bounds__(256) void init_h(const float* __restrict__ eh,
                                              unsigned short* __restrict__ Hb,
                                              unsigned* __restrict__ cnt) {
  if (blockIdx.x == 0) {   // reset all barrier counters each launch (graph replays!)
    for (int k = threadIdx.x; k < 4096; k += 256) cnt[k] = 0;
  }
  int i = (blockIdx.x * 256 + threadIdx.x) * 4;
  if (i >= BB_ * HH_) return;
  float4 v = *(const float4*)(eh + i);
  *(ushort4*)(Hb + i) = make_ushort4(f2b(v.x), f2b(v.y), f2b(v.z), f2b(v.w));
}

// ---------- big GEMM: out[M x ldo] = A[Mpad x 1024](bf16) @ W[N x ldw]^T + bias ----------
// m97 structure: 128x128 tile, BK=32, global_load_lds(16B), 4 waves each 64x64.
// Bijective XCD swizzle (m204): consecutive m-blocks (sharing a W chunk) on one XCD L2.
__global__ __launch_bounds__(256) void gemm128_bt(
    const unsigned short* __restrict__ A, const unsigned short* __restrict__ W,
    const float* __restrict__ bias, float* __restrict__ out, long ldo,
    int Mtiles, int ldw, int Mvalid) {
  __shared__ __align__(16) unsigned short As[128 * 32];
  __shared__ __align__(16) unsigned short Bs[128 * 32];
  int nwg = gridDim.x;
  int orig = blockIdx.x;
  int xcd = orig & 7, lid = orig >> 3;
  int qq = nwg >> 3, rr = nwg & 7;
  int wgid = (xcd < rr ? xcd * (qq + 1) : rr * (qq + 1) + (xcd - rr) * qq) + lid;
  int m0 = (wgid % Mtiles) * 128;
  int n0 = (wgid / Mtiles) * 128;
  int tid = threadIdx.x;
  int w = tid >> 6, l = tid & 63;
  int srow = tid >> 2, scg = tid & 3;
  int mw = (w & 1) * 64, nw = (w >> 1) * 64;

  const unsigned short* Ag0 = A + (long)(m0 + srow) * 1024 + scg * 8;
  const unsigned short* Ag1 = Ag0 + 64 * 1024;
  const unsigned short* Wg0 = W + (long)(n0 + srow) * ldw + scg * 8;
  const unsigned short* Wg1 = Wg0 + (long)64 * ldw;
  unsigned short* lA0 = As + tid * 8;
  unsigned short* lA1 = As + 2048 + tid * 8;
  unsigned short* lB0 = Bs + tid * 8;
  unsigned short* lB1 = Bs + 2048 + tid * 8;

  f32x4 zero = {0.f, 0.f, 0.f, 0.f};
  f32x4 acc[4][4];
#pragma unroll
  for (int i = 0; i < 4; ++i)
#pragma unroll
    for (int j = 0; j < 4; ++j) acc[i][j] = zero;

  for (int k0 = 0; k0 < 1024; k0 += 32) {
    __syncthreads();
    gload16(Ag0 + k0, lA0);
    gload16(Ag1 + k0, lA1);
    gload16(Wg0 + k0, lB0);
    gload16(Wg1 + k0, lB1);
    __syncthreads();
    bf16x8 af[4], bg[4];
#pragma unroll
    for (int mt = 0; mt < 4; ++mt)
      af[mt] = ldb8(As + (mw + mt * 16 + (l & 15)) * 32 + (l >> 4) * 8);
#pragma unroll
    for (int nt = 0; nt < 4; ++nt)
      bg[nt] = ldb8(Bs + (nw + nt * 16 + (l & 15)) * 32 + (l >> 4) * 8);
#pragma unroll
    for (int mt = 0; mt < 4; ++mt)
#pragma unroll
      for (int nt = 0; nt < 4; ++nt)
        acc[mt][nt] = __builtin_amdgcn_mfma_f32_16x16x32_bf16(af[mt], bg[nt], acc[mt][nt], 0, 0, 0);
  }

  int lr = (l >> 4) * 4, lc = l & 15;
#pragma unroll
  for (int nt = 0; nt < 4; ++nt) {
    int col = n0 + nw + nt * 16 + lc;
    float bv = bias[col];
#pragma unroll
    for (int mt = 0; mt < 4; ++mt) {
#pragma unroll
      for (int r = 0; r < 4; ++r) {
        int m = m0 + mw + mt * 16 + lr + r;
        if (m < Mvalid) out[(long)m * ldo + col] = acc[mt][nt][r] + bv;
      }
    }
  }
}

// ---------- fused 25-step decode loop (persistent, 256 blocks x 256 threads) ----------
// Plain launch (NOT cooperative): 256 blocks x 256 thr x 41KB LDS = 1 block/CU on
// 256 CUs -> trivially co-resident; barriers are hand-rolled relaxed atomics.
// Streams (KEYS/enc/GA) read via agent-coherent loads => no L2 allocation => the
// step-invariant weight fragments stay resident in each block's own XCD L2.
__global__ __launch_bounds__(256) void decode_loop(
    const unsigned short* __restrict__ WaB, const unsigned short* __restrict__ WhhB,
    const unsigned short* __restrict__ WihB, const float* __restrict__ ba,
    const float* __restrict__ bhh, const float* __restrict__ Va,
    const float* __restrict__ KEYS, const float* __restrict__ enc,
    const float* __restrict__ GA, const float* __restrict__ ehid,
    float* __restrict__ Qf, float* __restrict__ GHf, float* __restrict__ SC,
    unsigned short* __restrict__ CTXB, unsigned short* __restrict__ Hb,
    unsigned short* __restrict__ HALLB, unsigned* __restrict__ cnt) {
  __shared__ __align__(16) char AsC[16 * 2048];   // 16 rows x 1024 bf16 (swizzled)
  __shared__ float qs[1024];
  __shared__ float vas[1024];
  __shared__ float wgt[64];

  const int tid = threadIdx.x, bid = blockIdx.x;
  const int wv = tid >> 6, l = tid & 63;
  const int lc = l & 15, hi = l >> 4, ko = hi * 8, lr4 = hi * 4;

  // ---- phase-1 mapping (identical to round 2): wave owns chunk nch of [q:64|gh:192]
  const int m1 = (bid & 3) * 16;
  const int nch = (bid >> 2) * 4 + wv;           // 0..255
  const int n1 = nch * 16;
  const unsigned short* B1;
  float* o1; long ldo1; float bv1;
  if (n1 < 1024) {
    B1 = WaB + (long)(n1 + lc) * 1024 + ko;
    o1 = Qf + n1; ldo1 = 1024; bv1 = ba[n1 + lc];
  } else {
    B1 = WhhB + (long)(n1 - 1024 + lc) * 1024 + ko;
    o1 = GHf + (n1 - 1024); ldo1 = 3072; bv1 = bhh[n1 - 1024 + lc];
  }

  // ---- phase-2 mapping
  const int b2 = bid >> 2;                        // batch
  const int jq = (bid & 3) * 4 + wv;              // 0..15 score-wave id within batch
  const int c2 = (bid & 3) * 256 + tid;           // ctx column

  // ---- phase-3 mapping (identical to round 2)
  const int m3 = (bid & 3) * 16, n3 = (bid >> 2) * 16;
  const unsigned short* Bg0 = WihB + (long)(n3 + lc) * 2048 + 1024 + ko;
  const unsigned short* Bg1 = Bg0 + (long)1024 * 2048;
  const unsigned short* Bg2 = Bg0 + (long)2048 * 2048;
  const int ig = n3 + lc;
  float hreg[4];
  if (tid < 64) {
#pragma unroll
    for (int r = 0; r < 4; ++r) hreg[r] = ehid[(long)(m3 + lr4 + r) * HH_ + ig];
  }

  // stage Va once (static)
#pragma unroll
  for (int j = 0; j < 4; ++j) vas[tid + j * 256] = Va[tid + j * 256];

  const f32x4 zero = {0.f, 0.f, 0.f, 0.f};
  unsigned gB = 0;

  for (int t = 0; t < TT_; ++t) {
    // ---- P1: q (blocks 0-63) | gh (blocks 64-255)
    {
#pragma unroll
      for (int i = 0; i < 16; ++i) {
        u64 v = cld8((const u64*)(Hb + (long)(m1 + i) * HH_) + tid);
        *(u64*)(AsC + ((i * 2048 + tid * 8) ^ ((i & 7) << 4))) = v;
      }
      __syncthreads();
      f32x4 acc = zero;
#pragma unroll 8
      for (int k = 0; k < 1024; k += 32) {
        bf16x8 af = *(const bf16x8*)(AsC + ((lc * 2048 + (k + ko) * 2) ^ ((lc & 7) << 4)));
        acc = __builtin_amdgcn_mfma_f32_16x16x32_bf16(af, ldb8(B1 + k), acc, 0, 0, 0);
      }
#pragma unroll
      for (int r = 0; r < 4; ++r)
        cstf(o1 + (long)(m1 + lr4 + r) * ldo1 + lc, acc[r] + bv1);
    }
    // ---- qbar: q producers (blocks 0-63) signal; everyone waits. gh overlaps attn.
    __syncthreads();
    if (tid == 0) {
      if (bid < 64) cadd(cnt + CNT_QBAR);
      while (cldu(cnt + CNT_QBAR) < (unsigned)(t + 1) * 64u) __builtin_amdgcn_s_sleep(2);
    }
    __syncthreads();

    // ---- P2a: scores for batch b2, this wave handles s = jq, jq+16, ...
    {
#pragma unroll
      for (int j = 0; j < 4; ++j)
        qs[tid + j * 256] = cldf(Qf + (long)b2 * HH_ + tid + j * 256);
      __syncthreads();
      for (int s = jq; s < SS_; s += 16) {
        const float* kr = KEYS + ((long)b2 * SS_ + s) * HH_;
        float p = 0.f;
#pragma unroll
        for (int j = 0; j < 16; ++j) {
          int hh = l + j * 64;
          p += fast_tanh(qs[hh] + cldf(kr + hh)) * vas[hh];
        }
#pragma unroll
        for (int off = 32; off; off >>= 1) p += __shfl_down(p, off);
        if (l == 0) cstf(SC + (long)b2 * 64 + s, p);
      }
    }
    // ---- mini-barrier: the 4 blocks of batch b2
    __syncthreads();
    if (tid == 0) {
      unsigned* mc = cnt + CNT_MINI + b2 * 32;
      cadd(mc);
      while (cldu(mc) < (unsigned)(t + 1) * 4u) __builtin_amdgcn_s_sleep(2);
    }
    __syncthreads();

    // ---- P2b: softmax (identical math) + ctx quarter
    {
      if (tid < 64) {
        float v = (tid < SS_) ? cldf(SC + (long)b2 * 64 + tid) : -1e30f;
        float m = v;
#pragma unroll
        for (int off = 32; off; off >>= 1) m = fmaxf(m, __shfl_down(m, off));
        m = __shfl(m, 0);
        float e = (tid < SS_) ? __expf(v - m) : 0.f;
        float ssum = e;
#pragma unroll
        for (int off = 32; off; off >>= 1) ssum += __shfl_down(ssum, off);
        ssum = __shfl(ssum, 0);
        if (tid < SS_) wgt[tid] = e / ssum;
      }
      __syncthreads();
      {
        const float* ep = enc + (long)b2 * SS_ * HH_ + c2;
        float a0 = 0.f;
#pragma unroll 10
        for (int s = 0; s < SS_; ++s)
          a0 += wgt[s] * cldf(ep + (long)s * HH_);
        unsigned hb16 = (unsigned)f2b(a0);
        unsigned ob = (unsigned)__shfl_xor((int)hb16, 1);
        if ((tid & 1) == 0)
          cst4((unsigned*)(CTXB + (long)b2 * HH_ + c2), hb16 | (ob << 16));
      }
    }
    gbarG(cnt, ++gB);

    // ---- P3: gx(ctx) 3 gates + GRU fuse -> h_new (wave 0, tile (m3,n3))
    {
#pragma unroll
      for (int i = 0; i < 16; ++i) {   // stage CTXB rows m3..m3+15 (all 4 waves)
        u64 v = cld8((const u64*)(CTXB + (long)(m3 + i) * HH_) + tid);
        *(u64*)(AsC + ((i * 2048 + tid * 8) ^ ((i & 7) << 4))) = v;
      }
      __syncthreads();
      if (tid < 64) {
        f32x4 ar = zero, az = zero, an_ = zero;
#pragma unroll 8
        for (int k = 0; k < 1024; k += 32) {
          bf16x8 a = *(const bf16x8*)(AsC + ((lc * 2048 + (k + ko) * 2) ^ ((lc & 7) << 4)));
          ar = __builtin_amdgcn_mfma_f32_16x16x32_bf16(a, ldb8(Bg0 + k), ar, 0, 0, 0);
          az = __builtin_amdgcn_mfma_f32_16x16x32_bf16(a, ldb8(Bg1 + k), az, 0, 0, 0);
          an_ = __builtin_amdgcn_mfma_f32_16x16x32_bf16(a, ldb8(Bg2 + k), an_, 0, 0, 0);
        }
#pragma unroll
        for (int r = 0; r < 4; ++r) {
          int bb = m3 + lr4 + r;
          long rowBT = (long)bb * TT_ + t;
          const float* ga = GA + rowBT * 3072;
          const float* gh = GHf + (long)bb * 3072;
          float rr = fast_sigmoid(cldf(ga + ig) + ar[r] + cldf(gh + ig));
          float zz = fast_sigmoid(cldf(ga + 1024 + ig) + az[r] + cldf(gh + 1024 + ig));
          float nn = fast_tanh(cldf(ga + 2048 + ig) + an_[r] + rr * cldf(gh + 2048 + ig));
          float hnew = (1.f - zz) * nn + zz * hreg[r];
          hreg[r] = hnew;
          unsigned hb = (unsigned)f2b(hnew);
          unsigned ob = (unsigned)__shfl_xor((int)hb, 1);
          if ((lc & 1) == 0)
            cst4((unsigned*)(Hb + (long)bb * HH_ + ig), hb | (ob << 16));
          HALLB[rowBT * HH_ + ig] = (unsigned short)hb;
        }
      }
    }
    if (t < TT_ - 1) gbarG(cnt, ++gB);
  }
}

extern "C" void kernel_launch(void* const* d_in, const int* in_sizes, int n_in,
                              void* d_out, int out_size, void* d_ws, size_t ws_size,
                              hipStream_t stream) {
  (void)in_sizes; (void)n_in; (void)out_size; (void)ws_size;
  const float* enc  = (const float*)d_in[0];
  const float* ehid = (const float*)d_in[1];
  const int*   tgt  = (const int*)d_in[2];
  const float* emb  = (const float*)d_in[3];
  const float* Wa   = (const float*)d_in[4];
  const float* ba   = (const float*)d_in[5];
  const float* Ua   = (const float*)d_in[6];
  const float* bu   = (const float*)d_in[7];
  const float* Va   = (const float*)d_in[8];
  const float* Wih  = (const float*)d_in[10];
  const float* bih  = (const float*)d_in[11];
  const float* Whh  = (const float*)d_in[12];
  const float* bhh  = (const float*)d_in[13];
  const float* Wout = (const float*)d_in[14];
  const float* bout = (const float*)d_in[15];
  float* out = (float*)d_out;

  char* p = (char*)d_ws;
  auto alloc = [&](size_t bytes) { char* r = p; p += (bytes + 255) & ~(size_t)255; return r; };
  unsigned short* WOUTB = (unsigned short*)alloc((size_t)VV_ * HH_ * 2);
  unsigned short* WIHB  = (unsigned short*)alloc((size_t)3072 * 2048 * 2);
  unsigned short* WHHB  = (unsigned short*)alloc((size_t)3072 * 1024 * 2);
  unsigned short* WAB   = (unsigned short*)alloc((size_t)1024 * 1024 * 2);
  unsigned short* UAB   = (unsigned short*)alloc((size_t)1024 * 1024 * 2);
  unsigned short* ENCB  = (unsigned short*)alloc((size_t)BB_ * SS_ * HH_ * 2);
  unsigned short* XEMB  = (unsigned short*)alloc((size_t)1664 * HH_ * 2);  // pad 1600->1664
  unsigned short* HALLB = (unsigned short*)alloc((size_t)1664 * HH_ * 2);
  float* KEYS = (float*)alloc((size_t)BB_ * SS_ * HH_ * 4);
  float* GA   = (float*)alloc((size_t)1600 * 3072 * 4);
  float* GHf  = (float*)alloc((size_t)BB_ * 3072 * 4);
  float* Qf   = (float*)alloc((size_t)BB_ * HH_ * 4);
  float* SCf  = (float*)alloc((size_t)BB_ * 64 * 4);
  unsigned short* Hb = (unsigned short*)alloc((size_t)BB_ * HH_ * 2);
  unsigned short* CTXB = (unsigned short*)alloc((size_t)BB_ * HH_ * 2);
  unsigned* CNT = (unsigned*)alloc(4096 * 4);

  auto cvt = [&](const float* s, unsigned short* d, long n) {
    cvt_bf16<<<dim3((unsigned)((n / 4 + 255) / 256)), dim3(256), 0, stream>>>(s, d, n);
  };
  cvt(Wout, WOUTB, (long)VV_ * HH_);
  cvt(Wih, WIHB, (long)3072 * 2048);
  cvt(Whh, WHHB, (long)3072 * 1024);
  cvt(Wa, WAB, (long)1024 * 1024);
  cvt(Ua, UAB, (long)1024 * 1024);
  cvt(enc, ENCB, (long)BB_ * SS_ * HH_);
  embed_gather<<<dim3(1600 * HH_ / 4 / 256), dim3(256), 0, stream>>>(tgt, emb, XEMB);
  init_h<<<dim3(BB_ * HH_ / 4 / 256), dim3(256), 0, stream>>>(ehid, Hb, CNT);

  // keys_proj = enc @ Ua^T + bu : [3200,1024]
  gemm128_bt<<<dim3(25 * 8), dim3(256), 0, stream>>>(ENCB, UAB, bu, KEYS, (long)1024, 25, 1024, 3200);
  // gA = Xemb @ W_ih[:, :H]^T + b_ih : [1600,3072]
  gemm128_bt<<<dim3(13 * 24), dim3(256), 0, stream>>>(XEMB, WIHB, bih, GA, (long)3072, 13, 2048, 1600);

  // fused 25-step decode loop: plain launch (1 block/CU => co-resident; hand barriers)
  decode_loop<<<dim3(256), dim3(256), 0, stream>>>(
      WAB, WHHB, WIHB, ba, bhh, Va, KEYS, enc, GA, ehid,
      Qf, GHf, SCf, CTXB, Hb, HALLB, CNT);

  // logits = Hall @ Wout^T + bout, rows are (b*25+t) -> out[B,T,V] directly
  gemm128_bt<<<dim3(13 * 250), dim3(256), 0, stream>>>(HALLB, WOUTB, bout, out, (long)VV_, 13, 1024, 1600);
}

// Round 5
// 1657.481 us; speedup vs baseline: 3.1310x; 1.0500x over previous
//
#include <hip/hip_runtime.h>
#include <hip/hip_bf16.h>

#define BB_ 64
#define SS_ 50
#define TT_ 25
#define HH_ 1024
#define VV_ 32000

typedef __bf16 bf16x8 __attribute__((ext_vector_type(8)));
typedef float f32x4 __attribute__((ext_vector_type(4)));
typedef unsigned long long u64;

__device__ __forceinline__ unsigned short f2b(float f) {
  unsigned u = __float_as_uint(f);
  u = (u + 0x7FFFu + ((u >> 16) & 1u)) >> 16;  // RNE
  return (unsigned short)u;
}
__device__ __forceinline__ float b2f_(unsigned short s) {
  return __uint_as_float((unsigned)s << 16);
}
__device__ __forceinline__ float fast_tanh(float x) {
  float e = __expf(2.f * x);
  return 1.f - 2.f / (e + 1.f);
}
__device__ __forceinline__ float fast_sigmoid(float x) {
  return 1.f / (1.f + __expf(-x));
}
__device__ __forceinline__ void gload16(const void* g, void* l) {
  __builtin_amdgcn_global_load_lds((const __attribute__((address_space(1))) void*)g,
                                   (__attribute__((address_space(3))) void*)l, 16, 0, 0);
}
__device__ __forceinline__ bf16x8 ldb8(const unsigned short* p) {
  return *(const bf16x8*)p;
}

// ---- agent-scope coherent STORES (sc0 sc1): write through to the coherence point
// so consumers on other XCDs can fetch fresh data. Consumers use NORMAL cached loads
// on rotating (per-step fresh) addresses -> L2-shared within an XCD, no staleness.
__device__ __forceinline__ void cstf(float* p, float v) {
  __hip_atomic_store(p, v, __ATOMIC_RELAXED, __HIP_MEMORY_SCOPE_AGENT);
}
__device__ __forceinline__ void cst4(unsigned* p, unsigned v) {
  __hip_atomic_store(p, v, __ATOMIC_RELAXED, __HIP_MEMORY_SCOPE_AGENT);
}
__device__ __forceinline__ unsigned cadd(unsigned* p) {
  return __hip_atomic_fetch_add(p, 1u, __ATOMIC_RELAXED, __HIP_MEMORY_SCOPE_AGENT);
}
__device__ __forceinline__ unsigned cldu(const unsigned* p) {
  return __hip_atomic_load(p, __ATOMIC_RELAXED, __HIP_MEMORY_SCOPE_AGENT);
}

// CNT layout (dwords): [g*32] g<8 group counters | [256] root | [288] epoch
//                      [320] qbar | [384 + b*32] b<64 per-batch mini counters
#define CNT_ROOT 256
#define CNT_EPOCH 288
#define CNT_QBAR 320
#define CNT_MINI 384

// hierarchical grid barrier #n (1-indexed, monotonic)
__device__ __forceinline__ void gbarG(unsigned* cnt, unsigned n) {
  __syncthreads();   // drains vmcnt -> this block's stores globally visible
  if (threadIdx.x == 0) {
    unsigned g = blockIdx.x & 7u;
    unsigned old = cadd(cnt + g * 32);
    if (old == n * 32u - 1u) {
      unsigned r = cadd(cnt + CNT_ROOT);
      if (r == n * 8u - 1u) cst4(cnt + CNT_EPOCH, n);
    }
    while (cldu(cnt + CNT_EPOCH) < n) __builtin_amdgcn_s_sleep(2);
  }
  __syncthreads();
}

// ---------- converts / gathers ----------
__global__ __launch_bounds__(256) void cvt_bf16(const float* __restrict__ src,
                                                unsigned short* __restrict__ dst, long n) {
  long i = ((long)blockIdx.x * 256 + threadIdx.x) * 4;
  if (i >= n) return;
  float4 v = *(const float4*)(src + i);
  *(ushort4*)(dst + i) = make_ushort4(f2b(v.x), f2b(v.y), f2b(v.z), f2b(v.w));
}

__global__ __launch_bounds__(256) void embed_gather(const int* __restrict__ tgt,
                                                    const float* __restrict__ emb,
                                                    unsigned short* __restrict__ X) {
  long idx = ((long)blockIdx.x * 256 + threadIdx.x) * 4;
  if (idx >= (long)1600 * HH_) return;
  int col = (int)(idx & (HH_ - 1));
  int r = (int)(idx >> 10);          // row = b*25 + t
  int t = r % 25;
  int tok = (t == 0) ? 1 : tgt[r - 1];   // SOS=1; tgt flat [B,T]
  float4 v = *(const float4*)(emb + (long)tok * HH_ + col);
  *(ushort4*)(X + idx) = make_ushort4(f2b(v.x), f2b(v.y), f2b(v.z), f2b(v.w));
}

__global__ __launch_bounds__(256) void init_h(const float* __restrict__ eh,
                                              unsigned short* __restrict__ HBROT,
                                              unsigned* __restrict__ cnt) {
  if (blockIdx.x == 0) {   // reset all barrier counters each launch (graph replays!)
    for (int k = threadIdx.x; k < 4096; k += 256) cnt[k] = 0;
  }
  int i = (blockIdx.x * 256 + threadIdx.x) * 4;
  if (i >= BB_ * HH_) return;
  float4 v = *(const float4*)(eh + i);
  *(ushort4*)(HBROT + i) = make_ushort4(f2b(v.x), f2b(v.y), f2b(v.z), f2b(v.w));  // slot 0
}

// ---------- big GEMM: out[M x ldo] = A[Mpad x 1024](bf16) @ W[N x ldw]^T + bias ----------
__global__ __launch_bounds__(256) void gemm128_bt(
    const unsigned short* __restrict__ A, const unsigned short* __restrict__ W,
    const float* __restrict__ bias, float* __restrict__ out, long ldo,
    int Mtiles, int ldw, int Mvalid) {
  __shared__ __align__(16) unsigned short As[128 * 32];
  __shared__ __align__(16) unsigned short Bs[128 * 32];
  int nwg = gridDim.x;
  int orig = blockIdx.x;
  int xcd = orig & 7, lid = orig >> 3;
  int qq = nwg >> 3, rr = nwg & 7;
  int wgid = (xcd < rr ? xcd * (qq + 1) : rr * (qq + 1) + (xcd - rr) * qq) + lid;
  int m0 = (wgid % Mtiles) * 128;
  int n0 = (wgid / Mtiles) * 128;
  int tid = threadIdx.x;
  int w = tid >> 6, l = tid & 63;
  int srow = tid >> 2, scg = tid & 3;
  int mw = (w & 1) * 64, nw = (w >> 1) * 64;

  const unsigned short* Ag0 = A + (long)(m0 + srow) * 1024 + scg * 8;
  const unsigned short* Ag1 = Ag0 + 64 * 1024;
  const unsigned short* Wg0 = W + (long)(n0 + srow) * ldw + scg * 8;
  const unsigned short* Wg1 = Wg0 + (long)64 * ldw;
  unsigned short* lA0 = As + tid * 8;
  unsigned short* lA1 = As + 2048 + tid * 8;
  unsigned short* lB0 = Bs + tid * 8;
  unsigned short* lB1 = Bs + 2048 + tid * 8;

  f32x4 zero = {0.f, 0.f, 0.f, 0.f};
  f32x4 acc[4][4];
#pragma unroll
  for (int i = 0; i < 4; ++i)
#pragma unroll
    for (int j = 0; j < 4; ++j) acc[i][j] = zero;

  for (int k0 = 0; k0 < 1024; k0 += 32) {
    __syncthreads();
    gload16(Ag0 + k0, lA0);
    gload16(Ag1 + k0, lA1);
    gload16(Wg0 + k0, lB0);
    gload16(Wg1 + k0, lB1);
    __syncthreads();
    bf16x8 af[4], bg[4];
#pragma unroll
    for (int mt = 0; mt < 4; ++mt)
      af[mt] = ldb8(As + (mw + mt * 16 + (l & 15)) * 32 + (l >> 4) * 8);
#pragma unroll
    for (int nt = 0; nt < 4; ++nt)
      bg[nt] = ldb8(Bs + (nw + nt * 16 + (l & 15)) * 32 + (l >> 4) * 8);
#pragma unroll
    for (int mt = 0; mt < 4; ++mt)
#pragma unroll
      for (int nt = 0; nt < 4; ++nt)
        acc[mt][nt] = __builtin_amdgcn_mfma_f32_16x16x32_bf16(af[mt], bg[nt], acc[mt][nt], 0, 0, 0);
  }

  int lr = (l >> 4) * 4, lc = l & 15;
#pragma unroll
  for (int nt = 0; nt < 4; ++nt) {
    int col = n0 + nw + nt * 16 + lc;
    float bv = bias[col];
#pragma unroll
    for (int mt = 0; mt < 4; ++mt) {
#pragma unroll
      for (int r = 0; r < 4; ++r) {
        int m = m0 + mw + mt * 16 + lr + r;
        if (m < Mvalid) out[(long)m * ldo + col] = acc[mt][nt][r] + bv;
      }
    }
  }
}

// ---------- fused 25-step decode loop (persistent, 256 blocks x 256 threads) ----------
// XCD-aware mapping (xcd=bid&7, lxb=bid>>3): the 4 m-copies of every weight chunk and
// all 4 blocks of an attention batch share one XCD L2 -> per-XCD hot set ~3.4MB (fits).
// Inter-phase data rotates through per-step slots: coherent (write-through) stores,
// NORMAL cached reads on fresh addresses (L2-dedup within an XCD, no staleness).
__global__ __launch_bounds__(256) void decode_loop(
    const unsigned short* __restrict__ WaB, const unsigned short* __restrict__ WhhB,
    const unsigned short* __restrict__ WihB, const float* __restrict__ ba,
    const float* __restrict__ bhh, const float* __restrict__ Va,
    const unsigned short* __restrict__ KEYSB, const unsigned short* __restrict__ ENCB,
    const float* __restrict__ GA, const float* __restrict__ ehid,
    float* __restrict__ QROT, float* __restrict__ GHROT, float* __restrict__ SCROT,
    unsigned short* __restrict__ CTXROT, unsigned short* __restrict__ HBROT,
    unsigned short* __restrict__ HALLB, unsigned* __restrict__ cnt) {
  __shared__ __align__(16) char AsC[16 * 2048];   // 16 rows x 1024 bf16 (swizzled)
  __shared__ float qs[1024];
  __shared__ float vas[1024];
  __shared__ float wgt[64];

  const int tid = threadIdx.x, bid = blockIdx.x;
  const int wv = tid >> 6, l = tid & 63;
  const int lc = l & 15, hi = l >> 4, ko = hi * 8, lr4 = hi * 4;
  const int xcd = bid & 7, lxb = bid >> 3;
  const int mt_ = lxb & 3, cg = lxb >> 2;       // m-tile / chunk-group within XCD

  // ---- P1: tile (m1, n1); all 4 m-copies of chunk nch live on this XCD
  const int m1 = mt_ * 16;
  const int nch = xcd * 32 + cg * 4 + wv;        // 0..255 over [q:64 | gh:192]
  const int n1 = nch * 16;
  const bool isq = (n1 < 1024);
  const unsigned short* B1 = isq ? WaB + (long)(n1 + lc) * 1024 + ko
                                 : WhhB + (long)(n1 - 1024 + lc) * 1024 + ko;
  float* o1 = isq ? QROT + n1 : GHROT + (n1 - 1024);
  const long ldo1 = isq ? 1024 : 3072;
  const long slot1 = isq ? (long)BB_ * 1024 : (long)BB_ * 3072;
  const float bv1 = isq ? ba[n1 + lc] : bhh[n1 - 1024 + lc];

  // ---- P2: batch b2 owned entirely by this XCD (4 blocks, roles = mt_)
  const int b2 = xcd * 8 + cg;                   // 0..63
  const int jq = mt_ * 4 + wv;                   // 0..15 score-wave id
  const int c2 = mt_ * 256 + tid;                // ctx column quarter

  // ---- P3: tile (m3, n3); 4 m-copies of Wih chunk n3 on this XCD
  const int m3 = mt_ * 16, n3 = (xcd * 8 + cg) * 16;
  const unsigned short* Bg0 = WihB + (long)(n3 + lc) * 2048 + 1024 + ko;
  const unsigned short* Bg1 = Bg0 + (long)1024 * 2048;
  const unsigned short* Bg2 = Bg0 + (long)2048 * 2048;
  const int ig = n3 + lc;
  float hreg[4];
  if (tid < 64) {
#pragma unroll
    for (int r = 0; r < 4; ++r) hreg[r] = ehid[(long)(m3 + lr4 + r) * HH_ + ig];
  }

#pragma unroll
  for (int j = 0; j < 4; ++j) vas[tid + j * 256] = Va[tid + j * 256];

  const f32x4 zero = {0.f, 0.f, 0.f, 0.f};
  unsigned gB = 0;

  for (int t = 0; t < TT_; ++t) {
    // ---- P1: q | gh. Stage h rows (slot t, normal cached reads) -> LDS, MFMA.
    {
      const unsigned short* hbase = HBROT + (long)t * (BB_ * 1024);
#pragma unroll
      for (int i = 0; i < 16; ++i) {
        u64 v = *((const u64*)(hbase + (long)(m1 + i) * 1024) + tid);
        *(u64*)(AsC + ((i * 2048 + tid * 8) ^ ((i & 7) << 4))) = v;
      }
      __syncthreads();
      f32x4 acc = zero;
#pragma unroll 8
      for (int k = 0; k < 1024; k += 32) {
        bf16x8 af = *(const bf16x8*)(AsC + ((lc * 2048 + (k + ko) * 2) ^ ((lc & 7) << 4)));
        acc = __builtin_amdgcn_mfma_f32_16x16x32_bf16(af, ldb8(B1 + k), acc, 0, 0, 0);
      }
#pragma unroll
      for (int r = 0; r < 4; ++r)
        cstf(o1 + (long)t * slot1 + (long)(m1 + lr4 + r) * ldo1 + lc, acc[r] + bv1);
    }
    // ---- qbar: q producers (XCDs 0,1 = 64 blocks) signal; gh overlaps attention.
    __syncthreads();
    if (tid == 0) {
      if (xcd < 2) cadd(cnt + CNT_QBAR);
      while (cldu(cnt + CNT_QBAR) < (unsigned)(t + 1) * 64u) __builtin_amdgcn_s_sleep(2);
    }
    __syncthreads();

    // ---- P2a: scores for batch b2; this wave handles s = jq, jq+16, ...
    {
      const float* qsl = QROT + (long)t * (BB_ * 1024) + (long)b2 * 1024;
#pragma unroll
      for (int j = 0; j < 4; ++j)
        qs[tid + j * 256] = qsl[tid + j * 256];
      __syncthreads();
      for (int s = jq; s < SS_; s += 16) {
        const unsigned short* kr = KEYSB + ((long)b2 * SS_ + s) * 1024;
        float p = 0.f;
#pragma unroll
        for (int j = 0; j < 16; ++j) {
          int hh = l + j * 64;
          p += fast_tanh(qs[hh] + b2f_(kr[hh])) * vas[hh];
        }
#pragma unroll
        for (int off = 32; off; off >>= 1) p += __shfl_down(p, off);
        if (l == 0) cstf(SCROT + (long)t * 4096 + b2 * 64 + s, p);
      }
    }
    // ---- mini-barrier: the 4 blocks of batch b2 (same XCD)
    __syncthreads();
    if (tid == 0) {
      unsigned* mc = cnt + CNT_MINI + b2 * 32;
      cadd(mc);
      while (cldu(mc) < (unsigned)(t + 1) * 4u) __builtin_amdgcn_s_sleep(2);
    }
    __syncthreads();

    // ---- P2b: softmax (identical math) + ctx quarter (bf16 enc)
    {
      if (tid < 64) {
        float v = (tid < SS_) ? SCROT[(long)t * 4096 + b2 * 64 + tid] : -1e30f;
        float m = v;
#pragma unroll
        for (int off = 32; off; off >>= 1) m = fmaxf(m, __shfl_down(m, off));
        m = __shfl(m, 0);
        float e = (tid < SS_) ? __expf(v - m) : 0.f;
        float ssum = e;
#pragma unroll
        for (int off = 32; off; off >>= 1) ssum += __shfl_down(ssum, off);
        ssum = __shfl(ssum, 0);
        if (tid < SS_) wgt[tid] = e / ssum;
      }
      __syncthreads();
      {
        const unsigned short* ep = ENCB + (long)b2 * SS_ * 1024 + c2;
        float a0 = 0.f;
#pragma unroll 10
        for (int s = 0; s < SS_; ++s)
          a0 += wgt[s] * b2f_(ep[(long)s * 1024]);
        unsigned hb16 = (unsigned)f2b(a0);
        unsigned ob = (unsigned)__shfl_xor((int)hb16, 1);
        if ((tid & 1) == 0)
          cst4((unsigned*)(CTXROT + (long)t * (BB_ * 1024) + (long)b2 * 1024 + c2), hb16 | (ob << 16));
      }
    }
    gbarG(cnt, ++gB);

    // ---- P3: gx(ctx) 3 gates + GRU fuse -> h_new (wave 0, tile (m3,n3))
    {
      const unsigned short* cbase = CTXROT + (long)t * (BB_ * 1024);
#pragma unroll
      for (int i = 0; i < 16; ++i) {   // stage ctx rows m3..m3+15 (all 4 waves)
        u64 v = *((const u64*)(cbase + (long)(m3 + i) * 1024) + tid);
        *(u64*)(AsC + ((i * 2048 + tid * 8) ^ ((i & 7) << 4))) = v;
      }
      __syncthreads();
      if (tid < 64) {
        f32x4 ar = zero, az = zero, an_ = zero;
#pragma unroll 8
        for (int k = 0; k < 1024; k += 32) {
          bf16x8 a = *(const bf16x8*)(AsC + ((lc * 2048 + (k + ko) * 2) ^ ((lc & 7) << 4)));
          ar = __builtin_amdgcn_mfma_f32_16x16x32_bf16(a, ldb8(Bg0 + k), ar, 0, 0, 0);
          az = __builtin_amdgcn_mfma_f32_16x16x32_bf16(a, ldb8(Bg1 + k), az, 0, 0, 0);
          an_ = __builtin_amdgcn_mfma_f32_16x16x32_bf16(a, ldb8(Bg2 + k), an_, 0, 0, 0);
        }
        const float* ghb = GHROT + (long)t * (BB_ * 3072);
        unsigned short* hnb = HBROT + (long)(t + 1) * (BB_ * 1024);
#pragma unroll
        for (int r = 0; r < 4; ++r) {
          int bb = m3 + lr4 + r;
          long rowBT = (long)bb * TT_ + t;
          const float* ga = GA + rowBT * 3072;
          const float* gh = ghb + (long)bb * 3072;
          float rr = fast_sigmoid(ga[ig] + ar[r] + gh[ig]);
          float zz = fast_sigmoid(ga[1024 + ig] + az[r] + gh[1024 + ig]);
          float nn = fast_tanh(ga[2048 + ig] + an_[r] + rr * gh[2048 + ig]);
          float hnew = (1.f - zz) * nn + zz * hreg[r];
          hreg[r] = hnew;
          unsigned hb = (unsigned)f2b(hnew);
          unsigned ob = (unsigned)__shfl_xor((int)hb, 1);
          if ((lc & 1) == 0)
            cst4((unsigned*)(hnb + (long)bb * 1024 + ig), hb | (ob << 16));
          HALLB[rowBT * HH_ + ig] = (unsigned short)hb;
        }
      }
    }
    if (t < TT_ - 1) gbarG(cnt, ++gB);
  }
}

extern "C" void kernel_launch(void* const* d_in, const int* in_sizes, int n_in,
                              void* d_out, int out_size, void* d_ws, size_t ws_size,
                              hipStream_t stream) {
  (void)in_sizes; (void)n_in; (void)out_size; (void)ws_size;
  const float* enc  = (const float*)d_in[0];
  const float* ehid = (const float*)d_in[1];
  const int*   tgt  = (const int*)d_in[2];
  const float* emb  = (const float*)d_in[3];
  const float* Wa   = (const float*)d_in[4];
  const float* ba   = (const float*)d_in[5];
  const float* Ua   = (const float*)d_in[6];
  const float* bu   = (const float*)d_in[7];
  const float* Va   = (const float*)d_in[8];
  const float* Wih  = (const float*)d_in[10];
  const float* bih  = (const float*)d_in[11];
  const float* Whh  = (const float*)d_in[12];
  const float* bhh  = (const float*)d_in[13];
  const float* Wout = (const float*)d_in[14];
  const float* bout = (const float*)d_in[15];
  float* out = (float*)d_out;

  char* p = (char*)d_ws;
  auto alloc = [&](size_t bytes) { char* r = p; p += (bytes + 255) & ~(size_t)255; return r; };
  unsigned short* WOUTB = (unsigned short*)alloc((size_t)VV_ * HH_ * 2);
  unsigned short* WIHB  = (unsigned short*)alloc((size_t)3072 * 2048 * 2);
  unsigned short* WHHB  = (unsigned short*)alloc((size_t)3072 * 1024 * 2);
  unsigned short* WAB   = (unsigned short*)alloc((size_t)1024 * 1024 * 2);
  unsigned short* UAB   = (unsigned short*)alloc((size_t)1024 * 1024 * 2);
  unsigned short* ENCB  = (unsigned short*)alloc((size_t)BB_ * SS_ * HH_ * 2);
  unsigned short* XEMB  = (unsigned short*)alloc((size_t)1664 * HH_ * 2);  // pad 1600->1664
  unsigned short* HALLB = (unsigned short*)alloc((size_t)1664 * HH_ * 2);
  float* KEYS = (float*)alloc((size_t)BB_ * SS_ * HH_ * 4);
  unsigned short* KEYSB = (unsigned short*)alloc((size_t)BB_ * SS_ * HH_ * 2);
  float* GA   = (float*)alloc((size_t)1600 * 3072 * 4);
  // rotating per-step buffers (fresh addresses each step => safe normal cached reads)
  float* QROT  = (float*)alloc((size_t)TT_ * BB_ * 1024 * 4);
  float* GHROT = (float*)alloc((size_t)TT_ * BB_ * 3072 * 4);
  float* SCROT = (float*)alloc((size_t)TT_ * 4096 * 4);
  unsigned short* CTXROT = (unsigned short*)alloc((size_t)TT_ * BB_ * 1024 * 2);
  unsigned short* HBROT  = (unsigned short*)alloc((size_t)(TT_ + 1) * BB_ * 1024 * 2);
  unsigned* CNT = (unsigned*)alloc(4096 * 4);

  auto cvt = [&](const float* s, unsigned short* d, long n) {
    cvt_bf16<<<dim3((unsigned)((n / 4 + 255) / 256)), dim3(256), 0, stream>>>(s, d, n);
  };
  cvt(Wout, WOUTB, (long)VV_ * HH_);
  cvt(Wih, WIHB, (long)3072 * 2048);
  cvt(Whh, WHHB, (long)3072 * 1024);
  cvt(Wa, WAB, (long)1024 * 1024);
  cvt(Ua, UAB, (long)1024 * 1024);
  cvt(enc, ENCB, (long)BB_ * SS_ * HH_);
  embed_gather<<<dim3(1600 * HH_ / 4 / 256), dim3(256), 0, stream>>>(tgt, emb, XEMB);
  init_h<<<dim3(BB_ * HH_ / 4 / 256), dim3(256), 0, stream>>>(ehid, HBROT, CNT);

  // keys_proj = enc @ Ua^T + bu : [3200,1024], then bf16 for the decode stream
  gemm128_bt<<<dim3(25 * 8), dim3(256), 0, stream>>>(ENCB, UAB, bu, KEYS, (long)1024, 25, 1024, 3200);
  cvt(KEYS, KEYSB, (long)BB_ * SS_ * HH_);
  // gA = Xemb @ W_ih[:, :H]^T + b_ih : [1600,3072]
  gemm128_bt<<<dim3(13 * 24), dim3(256), 0, stream>>>(XEMB, WIHB, bih, GA, (long)3072, 13, 2048, 1600);

  // fused 25-step decode loop: plain launch (1 block/CU => co-resident; hand barriers)
  decode_loop<<<dim3(256), dim3(256), 0, stream>>>(
      WAB, WHHB, WIHB, ba, bhh, Va, KEYSB, ENCB, GA, ehid,
      QROT, GHROT, SCROT, CTXROT, HBROT, HALLB, CNT);

  // logits = Hall @ Wout^T + bout, rows are (b*25+t) -> out[B,T,V] directly
  gemm128_bt<<<dim3(13 * 250), dim3(256), 0, stream>>>(HALLB, WOUTB, bout, out, (long)VV_, 13, 1024, 1600);
}